// Round 1
// baseline (1181.041 us; speedup 1.0000x reference)
//
#include <hip/hip_runtime.h>
#include <math.h>

#define NS 65536
#define HD 256
#define NE 8

// ---------------------------------------------------------------------------
// 8x8 register-tile GEMM core: acc[8][8] += A_lds[m0+i][k] * W[k][c0+j]
// A in LDS (row stride sa, fp32, 16B-aligned rows), W in global (row stride ldw).
// K must be a multiple of 4.
// ---------------------------------------------------------------------------
__device__ __forceinline__ void mm8x8(float acc[8][8], const float* __restrict__ Alds,
                                      int sa, int m0, int c0,
                                      const float* __restrict__ W, int ldw, int K)
{
    for (int k = 0; k < K; k += 4) {
        float a[8][4];
        #pragma unroll
        for (int i = 0; i < 8; ++i) {
            const float4 v = *(const float4*)(Alds + (m0 + i) * sa + k);
            a[i][0] = v.x; a[i][1] = v.y; a[i][2] = v.z; a[i][3] = v.w;
        }
        float w[4][8];
        #pragma unroll
        for (int kk = 0; kk < 4; ++kk) {
            const float4 v0 = *(const float4*)(W + (size_t)(k + kk) * ldw + c0);
            const float4 v1 = *(const float4*)(W + (size_t)(k + kk) * ldw + c0 + 4);
            w[kk][0] = v0.x; w[kk][1] = v0.y; w[kk][2] = v0.z; w[kk][3] = v0.w;
            w[kk][4] = v1.x; w[kk][5] = v1.y; w[kk][6] = v1.z; w[kk][7] = v1.w;
        }
        #pragma unroll
        for (int i = 0; i < 8; ++i)
            #pragma unroll
            for (int kk = 0; kk < 4; ++kk)
                #pragma unroll
                for (int j = 0; j < 8; ++j)
                    acc[i][j] = fmaf(a[i][kk], w[kk][j], acc[i][j]);
    }
}

// 4x8 variant for the 128-wide head GEMMs
__device__ __forceinline__ void mm4x8(float acc[4][8], const float* __restrict__ Alds,
                                      int sa, int m0, int c0,
                                      const float* __restrict__ W, int ldw, int K)
{
    for (int k = 0; k < K; k += 4) {
        float a[4][4];
        #pragma unroll
        for (int i = 0; i < 4; ++i) {
            const float4 v = *(const float4*)(Alds + (m0 + i) * sa + k);
            a[i][0] = v.x; a[i][1] = v.y; a[i][2] = v.z; a[i][3] = v.w;
        }
        float w[4][8];
        #pragma unroll
        for (int kk = 0; kk < 4; ++kk) {
            const float4 v0 = *(const float4*)(W + (size_t)(k + kk) * ldw + c0);
            const float4 v1 = *(const float4*)(W + (size_t)(k + kk) * ldw + c0 + 4);
            w[kk][0] = v0.x; w[kk][1] = v0.y; w[kk][2] = v0.z; w[kk][3] = v0.w;
            w[kk][4] = v1.x; w[kk][5] = v1.y; w[kk][6] = v1.z; w[kk][7] = v1.w;
        }
        #pragma unroll
        for (int i = 0; i < 4; ++i)
            #pragma unroll
            for (int kk = 0; kk < 4; ++kk)
                #pragma unroll
                for (int j = 0; j < 8; ++j)
                    acc[i][j] = fmaf(a[i][kk], w[kk][j], acc[i][j]);
    }
}

// ---------------------------------------------------------------------------
// Kernel 1: posenc(xyz) -> trunk l1 (relu) -> trunk l2 (no act) -> gate
// (softmax + argmax + bucket-by-expert).  64 samples / block, 256 threads.
// ---------------------------------------------------------------------------
__global__ __launch_bounds__(256, 1) void trunk_kernel(
    const float* __restrict__ xyz,
    const float* __restrict__ W1, const float* __restrict__ b1,
    const float* __restrict__ W2, const float* __restrict__ b2,
    const float* __restrict__ Wg, const float* __restrict__ bg,
    float* __restrict__ h2out, float* __restrict__ gateout,
    int* __restrict__ counts, int* __restrict__ bucket)
{
    __shared__ float ex[64][64];     // posenc, 63 used (+1 pad)
    __shared__ float h1[64][260];    // stride 260: 16B-aligned, bank-offset 4
    __shared__ float h2[64][260];
    __shared__ int   lcount[NE];
    __shared__ int   lbase[NE];
    __shared__ int   lpos[64];
    __shared__ int   lexp[64];

    const int tid  = threadIdx.x;
    const int row0 = blockIdx.x * 64;

    if (tid < NE) lcount[tid] = 0;

    // --- positional encoding (threads 0..63, one sample each) ---
    if (tid < 64) {
        const int i = row0 + tid;
        const float x0 = xyz[3 * i], x1 = xyz[3 * i + 1], x2 = xyz[3 * i + 2];
        ex[tid][0] = x0; ex[tid][1] = x1; ex[tid][2] = x2;
        float f = 1.f;
        #pragma unroll
        for (int l = 0; l < 10; ++l) {
            ex[tid][3 + 6 * l + 0] = sinf(f * x0);
            ex[tid][3 + 6 * l + 1] = sinf(f * x1);
            ex[tid][3 + 6 * l + 2] = sinf(f * x2);
            ex[tid][3 + 6 * l + 3] = cosf(f * x0);
            ex[tid][3 + 6 * l + 4] = cosf(f * x1);
            ex[tid][3 + 6 * l + 5] = cosf(f * x2);
            f *= 2.f;
        }
        ex[tid][63] = 0.f;
    }
    __syncthreads();

    const int cg = tid & 31, rg = tid >> 5;
    const int c0 = cg * 8, m0 = rg * 8;

    // --- trunk layer 1: h1 = relu(ex @ W1 + b1), K = 63 ---
    {
        float acc[8][8] = {};
        mm8x8(acc, &ex[0][0], 64, m0, c0, W1, 256, 60);
        for (int kk = 60; kk < 63; ++kk) {
            #pragma unroll
            for (int i = 0; i < 8; ++i) {
                const float av = ex[m0 + i][kk];
                #pragma unroll
                for (int j = 0; j < 8; ++j)
                    acc[i][j] = fmaf(av, W1[kk * 256 + c0 + j], acc[i][j]);
            }
        }
        #pragma unroll
        for (int i = 0; i < 8; ++i)
            #pragma unroll
            for (int j = 0; j < 8; ++j)
                h1[m0 + i][c0 + j] = fmaxf(acc[i][j] + b1[c0 + j], 0.f);
    }
    __syncthreads();

    // --- trunk layer 2: h2 = h1 @ W2 + b2 (no relu); store LDS + global ---
    {
        float acc[8][8] = {};
        mm8x8(acc, &h1[0][0], 260, m0, c0, W2, 256, 256);
        #pragma unroll
        for (int i = 0; i < 8; ++i) {
            float vr[8];
            #pragma unroll
            for (int j = 0; j < 8; ++j) {
                vr[j] = acc[i][j] + b2[c0 + j];
                h2[m0 + i][c0 + j] = vr[j];
            }
            *(float4*)&h2out[(size_t)(row0 + m0 + i) * HD + c0]     = make_float4(vr[0], vr[1], vr[2], vr[3]);
            *(float4*)&h2out[(size_t)(row0 + m0 + i) * HD + c0 + 4] = make_float4(vr[4], vr[5], vr[6], vr[7]);
        }
    }
    __syncthreads();

    // --- gate: logits = h2 @ Wg + bg; softmax top-1; bucket by expert ---
    if (tid < 64) {
        const int i = row0 + tid;
        float lg[NE];
        #pragma unroll
        for (int e = 0; e < NE; ++e) lg[e] = bg[e];
        for (int k = 0; k < HD; ++k) {
            const float hv = h2[tid][k];
            #pragma unroll
            for (int e = 0; e < NE; ++e) lg[e] = fmaf(hv, Wg[k * NE + e], lg[e]);
        }
        int best = 0; float mx = lg[0];
        #pragma unroll
        for (int e = 1; e < NE; ++e) if (lg[e] > mx) { mx = lg[e]; best = e; }
        float s = 0.f;
        #pragma unroll
        for (int e = 0; e < NE; ++e) s += expf(lg[e] - mx);
        gateout[i] = 1.f / s;     // softmax score of argmax = exp(0)/sum
        lexp[tid] = best;
        lpos[tid] = atomicAdd(&lcount[best], 1);
    }
    __syncthreads();
    if (tid < NE) lbase[tid] = atomicAdd(&counts[tid], lcount[tid]);
    __syncthreads();
    if (tid < 64) {
        const int e = lexp[tid];
        bucket[e * NS + lbase[e] + lpos[tid]] = row0 + tid;
    }
}

// ---------------------------------------------------------------------------
// Kernel 2: per-expert fused 4-layer MLP + sigma head + color head.
// Grid = NE * 1024 blocks; block (e, t) handles 64 bucketed samples.
// ---------------------------------------------------------------------------
__global__ __launch_bounds__(256, 1) void expert_kernel(
    const float* __restrict__ h2buf, const float* __restrict__ gatebuf,
    const int* __restrict__ counts, const int* __restrict__ bucket,
    const float* __restrict__ We, const float* __restrict__ be,
    const float* __restrict__ dirs,
    const float* __restrict__ Ws1, const float* __restrict__ bs1,
    const float* __restrict__ Ws2, const float* __restrict__ bs2,
    const float* __restrict__ Wc1, const float* __restrict__ bc1,
    const float* __restrict__ Wc2, const float* __restrict__ bc2,
    float* __restrict__ outp)
{
    __shared__ float A[64][292];     // h / skip / out, cols 256..282 = posenc(dirs)
    __shared__ float Braw[16896];    // layer ping (stride 260) OR head s/c (stride 132)
    __shared__ int   idx[64];
    __shared__ float gatev[64];

    const int tid = threadIdx.x;
    const int e   = blockIdx.x >> 10;
    const int t   = blockIdx.x & 1023;
    const int cnt = counts[e];
    if (t * 64 >= cnt) return;
    const int nact = min(64, cnt - t * 64);

    if (tid < 64) {
        const int src = bucket[e * NS + t * 64 + min(tid, nact - 1)];
        idx[tid]   = src;
        gatev[tid] = gatebuf[src];
    }
    __syncthreads();

    // gather 64 rows of h2 into A
    {
        const int lane = tid & 63, g = tid >> 6;
        for (int m = g; m < 64; m += 4)
            *(float4*)&A[m][lane * 4] = *(const float4*)&h2buf[(size_t)idx[m] * HD + lane * 4];
    }
    __syncthreads();

    const int cg = tid & 31, rg = tid >> 5;
    const int c0 = cg * 8, m0 = rg * 8;
    const float* Wb = We + (size_t)e * 4 * HD * HD;
    const float* bb = be + e * 4 * HD;
    float* Bl = Braw;                      // layer view, stride 260

    // l0: B = relu(A @ W0 + b0)
    {
        float acc[8][8] = {};
        mm8x8(acc, &A[0][0], 292, m0, c0, Wb, HD, HD);
        #pragma unroll
        for (int i = 0; i < 8; ++i)
            #pragma unroll
            for (int j = 0; j < 8; ++j)
                Bl[(m0 + i) * 260 + c0 + j] = fmaxf(acc[i][j] + bb[c0 + j], 0.f);
    }
    __syncthreads();
    // l1: A = relu(B @ W1 + b1 + A)   (skip connection)
    {
        float acc[8][8] = {};
        mm8x8(acc, Bl, 260, m0, c0, Wb + HD * HD, HD, HD);
        #pragma unroll
        for (int i = 0; i < 8; ++i)
            #pragma unroll
            for (int j = 0; j < 8; ++j)
                A[m0 + i][c0 + j] = fmaxf(acc[i][j] + bb[HD + c0 + j] + A[m0 + i][c0 + j], 0.f);
    }
    __syncthreads();
    // l2: B = relu(A @ W2 + b2)
    {
        float acc[8][8] = {};
        mm8x8(acc, &A[0][0], 292, m0, c0, Wb + 2 * HD * HD, HD, HD);
        #pragma unroll
        for (int i = 0; i < 8; ++i)
            #pragma unroll
            for (int j = 0; j < 8; ++j)
                Bl[(m0 + i) * 260 + c0 + j] = fmaxf(acc[i][j] + bb[2 * HD + c0 + j], 0.f);
    }
    __syncthreads();
    // l3: A = gate * (B @ W3 + b3)   (no relu)
    {
        float acc[8][8] = {};
        mm8x8(acc, Bl, 260, m0, c0, Wb + 3 * HD * HD, HD, HD);
        #pragma unroll
        for (int i = 0; i < 8; ++i)
            #pragma unroll
            for (int j = 0; j < 8; ++j)
                A[m0 + i][c0 + j] = gatev[m0 + i] * (acc[i][j] + bb[3 * HD + c0 + j]);
    }
    __syncthreads();

    // --- sigma head s = relu(out @ Ws1 + bs1) -> Braw region1 (stride 132) ---
    const int cg2 = tid & 15, rg2 = tid >> 4;
    const int c02 = cg2 * 8, m02 = rg2 * 4;
    {
        float acc[4][8] = {};
        mm4x8(acc, &A[0][0], 292, m02, c02, Ws1, 128, 256);
        #pragma unroll
        for (int i = 0; i < 4; ++i)
            #pragma unroll
            for (int j = 0; j < 8; ++j)
                Braw[(m02 + i) * 132 + c02 + j] = fmaxf(acc[i][j] + bs1[c02 + j], 0.f);
    }
    // --- posenc(dirs) into A cols 256..282 (threads 0..63) ---
    if (tid < 64) {
        const int i = idx[tid];
        const float d0 = dirs[3 * i], d1 = dirs[3 * i + 1], d2 = dirs[3 * i + 2];
        A[tid][256] = d0; A[tid][257] = d1; A[tid][258] = d2;
        float f = 1.f;
        #pragma unroll
        for (int l = 0; l < 4; ++l) {
            A[tid][259 + 6 * l + 0] = sinf(f * d0);
            A[tid][259 + 6 * l + 1] = sinf(f * d1);
            A[tid][259 + 6 * l + 2] = sinf(f * d2);
            A[tid][259 + 6 * l + 3] = cosf(f * d0);
            A[tid][259 + 6 * l + 4] = cosf(f * d1);
            A[tid][259 + 6 * l + 5] = cosf(f * d2);
            f *= 2.f;
        }
    }
    __syncthreads();

    // --- sigma = softplus(s @ Ws2 + bs2) (threads 0..63, kept in register) ---
    float sigma_v = 0.f;
    if (tid < 64) {
        float acc = bs2[0];
        for (int k = 0; k < 128; ++k) acc = fmaf(Braw[tid * 132 + k], Ws2[k], acc);
        sigma_v = (acc > 20.f) ? acc : log1pf(expf(acc));
    }
    // --- color c = relu([out, ed] @ Wc1 + bc1) -> Braw region2 ---
    {
        float acc[4][8] = {};
        mm4x8(acc, &A[0][0], 292, m02, c02, Wc1, 128, 280);
        for (int kk = 280; kk < 283; ++kk) {   // K = 283 tail
            #pragma unroll
            for (int i = 0; i < 4; ++i) {
                const float av = A[m02 + i][kk];
                #pragma unroll
                for (int j = 0; j < 8; ++j)
                    acc[i][j] = fmaf(av, Wc1[kk * 128 + c02 + j], acc[i][j]);
            }
        }
        #pragma unroll
        for (int i = 0; i < 4; ++i)
            #pragma unroll
            for (int j = 0; j < 8; ++j)
                Braw[8448 + (m02 + i) * 132 + c02 + j] = fmaxf(acc[i][j] + bc1[c02 + j], 0.f);
    }
    __syncthreads();

    // --- rgb = sigmoid(c @ Wc2 + bc2); final [rgb, sigma] store ---
    if (tid < nact) {
        float r0 = bc2[0], r1 = bc2[1], r2 = bc2[2];
        for (int k = 0; k < 128; ++k) {
            const float cv = Braw[8448 + tid * 132 + k];
            r0 = fmaf(cv, Wc2[3 * k + 0], r0);
            r1 = fmaf(cv, Wc2[3 * k + 1], r1);
            r2 = fmaf(cv, Wc2[3 * k + 2], r2);
        }
        float4 o;
        o.x = 1.f / (1.f + expf(-r0));
        o.y = 1.f / (1.f + expf(-r1));
        o.z = 1.f / (1.f + expf(-r2));
        o.w = sigma_v;
        *(float4*)&outp[(size_t)idx[tid] * 4] = o;
    }
}

// ---------------------------------------------------------------------------
extern "C" void kernel_launch(void* const* d_in, const int* in_sizes, int n_in,
                              void* d_out, int out_size, void* d_ws, size_t ws_size,
                              hipStream_t stream)
{
    const float* xyz  = (const float*)d_in[0];
    const float* dirs = (const float*)d_in[1];
    const float* W1   = (const float*)d_in[2];
    const float* b1   = (const float*)d_in[3];
    const float* W2   = (const float*)d_in[4];
    const float* b2   = (const float*)d_in[5];
    const float* Wg   = (const float*)d_in[6];
    const float* bg   = (const float*)d_in[7];
    const float* We   = (const float*)d_in[8];
    const float* be   = (const float*)d_in[9];
    const float* Ws1  = (const float*)d_in[10];
    const float* bs1  = (const float*)d_in[11];
    const float* Ws2  = (const float*)d_in[12];
    const float* bs2  = (const float*)d_in[13];
    const float* Wc1  = (const float*)d_in[14];
    const float* bc1  = (const float*)d_in[15];
    const float* Wc2  = (const float*)d_in[16];
    const float* bc2  = (const float*)d_in[17];
    float* out = (float*)d_out;

    char* ws = (char*)d_ws;
    float* h2buf   = (float*)ws;                                   // N*H fp32 = 64 MB
    float* gatebuf = (float*)(ws + (size_t)NS * HD * 4);           // N fp32
    int*   counts  = (int*)  (ws + (size_t)NS * HD * 4 + (size_t)NS * 4);
    int*   bucket  = (int*)  (ws + (size_t)NS * HD * 4 + (size_t)NS * 4 + 256);

    hipMemsetAsync(counts, 0, NE * sizeof(int), stream);           // ws is poisoned 0xAA
    trunk_kernel<<<NS / 64, 256, 0, stream>>>(xyz, W1, b1, W2, b2, Wg, bg,
                                              h2buf, gatebuf, counts, bucket);
    expert_kernel<<<NE * 1024, 256, 0, stream>>>(h2buf, gatebuf, counts, bucket,
                                                 We, be, dirs, Ws1, bs1, Ws2, bs2,
                                                 Wc1, bc1, Wc2, bc2, out);
}

// Round 2
// 488.193 us; speedup vs baseline: 2.4192x; 2.4192x over previous
//
#include <hip/hip_runtime.h>
#include <math.h>

#define NS 65536
#define HD 256
#define NE 8
#define STR 292   // Apk row stride in uint32 (288 cols + pad; %32==4 -> <=2-way bank alias)

typedef short bh8 __attribute__((ext_vector_type(8)));   // 8 bf16 (A/B frag)
typedef float f4  __attribute__((ext_vector_type(4)));   // MFMA acc

// ---------------------------------------------------------------------------
// split-bf16 helpers: fp32 x ~= hi + lo (both bf16, RNE). packed = hi | lo<<16
// ---------------------------------------------------------------------------
__device__ __forceinline__ unsigned packf(float x) {
    unsigned u  = __float_as_uint(x);
    unsigned hb = (u + 0x7fffu + ((u >> 16) & 1u)) & 0xffff0000u;
    float    lo = x - __uint_as_float(hb);
    unsigned ul = __float_as_uint(lo);
    unsigned lb = (ul + 0x7fffu + ((ul >> 16) & 1u)) >> 16;
    return (hb >> 16) | (lb << 16);
}
__device__ __forceinline__ float unpackf(unsigned p) {
    return __uint_as_float(p << 16) + __uint_as_float(p & 0xffff0000u);
}
__device__ __forceinline__ void bfsplit(float x, unsigned short& h, unsigned short& l) {
    unsigned u  = __float_as_uint(x);
    unsigned hb = (u + 0x7fffu + ((u >> 16) & 1u)) & 0xffff0000u;
    h = (unsigned short)(hb >> 16);
    float    lo = x - __uint_as_float(hb);
    unsigned ul = __float_as_uint(lo);
    l = (unsigned short)((ul + 0x7fffu + ((ul >> 16) & 1u)) >> 16);
}

// 8 packed uint32 -> hi-plane short8 + lo-plane short8 (v_perm byte shuffles)
__device__ __forceinline__ void unpack8(const unsigned* p, bh8& h, bh8& l) {
    uint4 a = *(const uint4*)p;
    uint4 b = *(const uint4*)(p + 4);
    union { unsigned u[4]; bh8 v; } H, L;
    H.u[0] = __builtin_amdgcn_perm(a.y, a.x, 0x05040100u);
    H.u[1] = __builtin_amdgcn_perm(a.w, a.z, 0x05040100u);
    H.u[2] = __builtin_amdgcn_perm(b.y, b.x, 0x05040100u);
    H.u[3] = __builtin_amdgcn_perm(b.w, b.z, 0x05040100u);
    L.u[0] = __builtin_amdgcn_perm(a.y, a.x, 0x07060302u);
    L.u[1] = __builtin_amdgcn_perm(a.w, a.z, 0x07060302u);
    L.u[2] = __builtin_amdgcn_perm(b.y, b.x, 0x07060302u);
    L.u[3] = __builtin_amdgcn_perm(b.w, b.z, 0x07060302u);
    h = H.v; l = L.v;
}

// ---------------------------------------------------------------------------
// MFMA tile GEMM: acc[mt][nl] += A(64xK from LDS, packed) @ W(KxN, prepped frags)
// Wave covers ntiles [ntoff, ntoff+NTW). 3 MFMAs per tile = split-bf16 product.
// Prepped W frag layout: [(kc*NT + nt)*64 + lane]*8 bf16, hi plane then lo plane.
// ---------------------------------------------------------------------------
template<int KC, int NTW, int NT>
__device__ __forceinline__ void gemm_tile(const unsigned* __restrict__ Apk,
                                          const unsigned short* __restrict__ Wh,
                                          const unsigned short* __restrict__ Wl,
                                          int lane, int ntoff, f4 acc[4][NTW])
{
    const int q = lane >> 4, m = lane & 15;
    for (int kc = 0; kc < KC; ++kc) {
        bh8 ah[4], al[4];
        #pragma unroll
        for (int mt = 0; mt < 4; ++mt)
            unpack8(Apk + (mt * 16 + m) * STR + kc * 32 + q * 8, ah[mt], al[mt]);
        #pragma unroll
        for (int nl = 0; nl < NTW; ++nl) {
            const int fo = ((kc * NT + (ntoff + nl)) * 64 + lane) * 8;
            const bh8 bh = *(const bh8*)(Wh + fo);
            const bh8 bl = *(const bh8*)(Wl + fo);
            #pragma unroll
            for (int mt = 0; mt < 4; ++mt) {
                acc[mt][nl] = __builtin_amdgcn_mfma_f32_16x16x32_bf16(ah[mt], bh, acc[mt][nl], 0, 0, 0);
                acc[mt][nl] = __builtin_amdgcn_mfma_f32_16x16x32_bf16(al[mt], bh, acc[mt][nl], 0, 0, 0);
                acc[mt][nl] = __builtin_amdgcn_mfma_f32_16x16x32_bf16(ah[mt], bl, acc[mt][nl], 0, 0, 0);
            }
        }
    }
}

// ---------------------------------------------------------------------------
// Weight prep: shuffle + split into MFMA B-frag order.
// B-frag for lane L=(quad*16 + n15): elems j -> W[kc*32 + quad*8 + j][nt*16 + n15]
// ---------------------------------------------------------------------------
__global__ void prep_expert(const float* __restrict__ We, unsigned short* __restrict__ dst) {
    const int gid = blockIdx.x * 256 + threadIdx.x;        // 262144 threads
    const int nn = gid & 15, nt = (gid >> 4) & 15, qd = (gid >> 8) & 3;
    const int kc = (gid >> 10) & 7, el = gid >> 13;        // el = e*4 + l
    const int n = nt * 16 + nn;
    const float* src = We + (size_t)el * 65536 + (size_t)(kc * 32 + qd * 8) * 256 + n;
    union { unsigned short u[8]; bh8 v; } H, L;
    #pragma unroll
    for (int j = 0; j < 8; ++j) bfsplit(src[j * 256], H.u[j], L.u[j]);
    unsigned short* d = dst + (size_t)el * 131072 + (size_t)((kc * 16 + nt) * 64 + qd * 16 + nn) * 8;
    *(bh8*)d = H.v;
    *(bh8*)(d + 65536) = L.v;
}

__global__ void prep_head(const float* __restrict__ W, unsigned short* __restrict__ dst,
                          int KC, int Kreal) {
    const int gid = blockIdx.x * 256 + threadIdx.x;
    if (gid >= KC * 512) return;
    const int nn = gid & 15, nt = (gid >> 4) & 7, qd = (gid >> 7) & 3, kc = gid >> 9;
    const int n = nt * 16 + nn;
    union { unsigned short u[8]; bh8 v; } H, L;
    #pragma unroll
    for (int j = 0; j < 8; ++j) {
        const int k = kc * 32 + qd * 8 + j;
        const float x = (k < Kreal) ? W[k * 128 + n] : 0.f;
        bfsplit(x, H.u[j], L.u[j]);
    }
    unsigned short* d = dst + (size_t)((kc * 8 + nt) * 64 + qd * 16 + nn) * 8;
    *(bh8*)d = H.v;
    *(bh8*)(d + KC * 4096) = L.v;
}

// ---------------------------------------------------------------------------
// fp32 8x8 register-tile GEMM (trunk only — gate needs fp32-exact logits)
// ---------------------------------------------------------------------------
__device__ __forceinline__ void mm8x8(float acc[8][8], const float* __restrict__ Alds,
                                      int sa, int m0, int c0,
                                      const float* __restrict__ W, int ldw, int K)
{
    for (int k = 0; k < K; k += 4) {
        float a[8][4];
        #pragma unroll
        for (int i = 0; i < 8; ++i) {
            const float4 v = *(const float4*)(Alds + (m0 + i) * sa + k);
            a[i][0] = v.x; a[i][1] = v.y; a[i][2] = v.z; a[i][3] = v.w;
        }
        float w[4][8];
        #pragma unroll
        for (int kk = 0; kk < 4; ++kk) {
            const float4 v0 = *(const float4*)(W + (size_t)(k + kk) * ldw + c0);
            const float4 v1 = *(const float4*)(W + (size_t)(k + kk) * ldw + c0 + 4);
            w[kk][0] = v0.x; w[kk][1] = v0.y; w[kk][2] = v0.z; w[kk][3] = v0.w;
            w[kk][4] = v1.x; w[kk][5] = v1.y; w[kk][6] = v1.z; w[kk][7] = v1.w;
        }
        #pragma unroll
        for (int i = 0; i < 8; ++i)
            #pragma unroll
            for (int kk = 0; kk < 4; ++kk)
                #pragma unroll
                for (int j = 0; j < 8; ++j)
                    acc[i][j] = fmaf(a[i][kk], w[kk][j], acc[i][j]);
    }
}

// ---------------------------------------------------------------------------
// Kernel 1 (unchanged numerics, fp32): posenc -> trunk l1/l2 -> gate + bucket.
// h2 now written pre-split-packed for the expert kernel.
// ---------------------------------------------------------------------------
__global__ __launch_bounds__(256, 1) void trunk_kernel(
    const float* __restrict__ xyz,
    const float* __restrict__ W1, const float* __restrict__ b1,
    const float* __restrict__ W2, const float* __restrict__ b2,
    const float* __restrict__ Wg, const float* __restrict__ bg,
    unsigned* __restrict__ h2p, float* __restrict__ gateout,
    int* __restrict__ counts, int* __restrict__ bucket)
{
    __shared__ float ex[64][64];
    __shared__ float h1[64][260];
    __shared__ float h2[64][260];
    __shared__ int   lcount[NE];
    __shared__ int   lbase[NE];
    __shared__ int   lpos[64];
    __shared__ int   lexp[64];

    const int tid  = threadIdx.x;
    const int row0 = blockIdx.x * 64;

    if (tid < NE) lcount[tid] = 0;

    if (tid < 64) {
        const int i = row0 + tid;
        const float x0 = xyz[3 * i], x1 = xyz[3 * i + 1], x2 = xyz[3 * i + 2];
        ex[tid][0] = x0; ex[tid][1] = x1; ex[tid][2] = x2;
        float f = 1.f;
        #pragma unroll
        for (int l = 0; l < 10; ++l) {
            ex[tid][3 + 6 * l + 0] = sinf(f * x0);
            ex[tid][3 + 6 * l + 1] = sinf(f * x1);
            ex[tid][3 + 6 * l + 2] = sinf(f * x2);
            ex[tid][3 + 6 * l + 3] = cosf(f * x0);
            ex[tid][3 + 6 * l + 4] = cosf(f * x1);
            ex[tid][3 + 6 * l + 5] = cosf(f * x2);
            f *= 2.f;
        }
        ex[tid][63] = 0.f;
    }
    __syncthreads();

    const int cg = tid & 31, rg = tid >> 5;
    const int c0 = cg * 8, m0 = rg * 8;

    {   // l1 = relu(ex @ W1 + b1), K=63
        float acc[8][8] = {};
        mm8x8(acc, &ex[0][0], 64, m0, c0, W1, 256, 60);
        for (int kk = 60; kk < 63; ++kk) {
            #pragma unroll
            for (int i = 0; i < 8; ++i) {
                const float av = ex[m0 + i][kk];
                #pragma unroll
                for (int j = 0; j < 8; ++j)
                    acc[i][j] = fmaf(av, W1[kk * 256 + c0 + j], acc[i][j]);
            }
        }
        #pragma unroll
        for (int i = 0; i < 8; ++i)
            #pragma unroll
            for (int j = 0; j < 8; ++j)
                h1[m0 + i][c0 + j] = fmaxf(acc[i][j] + b1[c0 + j], 0.f);
    }
    __syncthreads();

    {   // l2 = h1 @ W2 + b2; LDS fp32 (gate) + global packed (expert input)
        float acc[8][8] = {};
        mm8x8(acc, &h1[0][0], 260, m0, c0, W2, 256, 256);
        #pragma unroll
        for (int i = 0; i < 8; ++i) {
            unsigned pk[8];
            #pragma unroll
            for (int j = 0; j < 8; ++j) {
                const float v = acc[i][j] + b2[c0 + j];
                h2[m0 + i][c0 + j] = v;
                pk[j] = packf(v);
            }
            *(uint4*)&h2p[(size_t)(row0 + m0 + i) * HD + c0]     = make_uint4(pk[0], pk[1], pk[2], pk[3]);
            *(uint4*)&h2p[(size_t)(row0 + m0 + i) * HD + c0 + 4] = make_uint4(pk[4], pk[5], pk[6], pk[7]);
        }
    }
    __syncthreads();

    if (tid < 64) {   // gate (fp32-exact)
        const int i = row0 + tid;
        float lg[NE];
        #pragma unroll
        for (int e = 0; e < NE; ++e) lg[e] = bg[e];
        for (int k = 0; k < HD; ++k) {
            const float hv = h2[tid][k];
            #pragma unroll
            for (int e = 0; e < NE; ++e) lg[e] = fmaf(hv, Wg[k * NE + e], lg[e]);
        }
        int best = 0; float mx = lg[0];
        #pragma unroll
        for (int e = 1; e < NE; ++e) if (lg[e] > mx) { mx = lg[e]; best = e; }
        float s = 0.f;
        #pragma unroll
        for (int e = 0; e < NE; ++e) s += expf(lg[e] - mx);
        gateout[i] = 1.f / s;
        lexp[tid] = best;
        lpos[tid] = atomicAdd(&lcount[best], 1);
    }
    __syncthreads();
    if (tid < NE) lbase[tid] = atomicAdd(&counts[tid], lcount[tid]);
    __syncthreads();
    if (tid < 64) {
        const int e = lexp[tid];
        bucket[e * NS + lbase[e] + lpos[tid]] = row0 + tid;
    }
}

// ---------------------------------------------------------------------------
// Kernel 2: split-bf16 MFMA expert MLP (4 layers, skip@l1, gate@l3) + both
// heads, fully fused in one 64-row block. Waves partition N. 2 blocks/CU.
// ---------------------------------------------------------------------------
__global__ __launch_bounds__(256, 2) void expert_kernel(
    const unsigned* __restrict__ h2p, const float* __restrict__ gatebuf,
    const int* __restrict__ counts, const int* __restrict__ bucket,
    const unsigned short* __restrict__ EWp, const float* __restrict__ be,
    const float* __restrict__ dirs,
    const unsigned short* __restrict__ Ws1p, const float* __restrict__ bs1,
    const float* __restrict__ Ws2, const float* __restrict__ bs2,
    const unsigned short* __restrict__ Wc1p, const float* __restrict__ bc1,
    const float* __restrict__ Wc2, const float* __restrict__ bc2,
    float* __restrict__ outp)
{
    __shared__ unsigned Apk[64 * STR];
    __shared__ int   idx[64];
    __shared__ float gatev[64];

    const int tid = threadIdx.x;
    const int e   = blockIdx.x >> 10;
    const int t   = blockIdx.x & 1023;
    const int cnt = counts[e];
    if (t * 64 >= cnt) return;
    const int nact = min(64, cnt - t * 64);

    if (tid < 64) {
        const int src = bucket[e * NS + t * 64 + min(tid, nact - 1)];
        idx[tid]   = src;
        gatev[tid] = gatebuf[src];
    }
    __syncthreads();

    // gather packed h2 rows + posenc(dirs) into Apk cols 256..287
    {
        const int row = tid >> 2, cb = (tid & 3) * 64;
        const unsigned* src = h2p + (size_t)idx[row] * HD + cb;
        #pragma unroll 4
        for (int c = 0; c < 64; c += 4)
            *(uint4*)&Apk[row * STR + cb + c] = *(const uint4*)(src + c);
    }
    if (tid < 64) {
        const int i = idx[tid];
        const float d0 = dirs[3 * i], d1 = dirs[3 * i + 1], d2 = dirs[3 * i + 2];
        unsigned* r = &Apk[tid * STR + 256];
        r[0] = packf(d0); r[1] = packf(d1); r[2] = packf(d2);
        float f = 1.f;
        #pragma unroll
        for (int l = 0; l < 4; ++l) {
            r[3 + 6 * l + 0] = packf(sinf(f * d0));
            r[3 + 6 * l + 1] = packf(sinf(f * d1));
            r[3 + 6 * l + 2] = packf(sinf(f * d2));
            r[3 + 6 * l + 3] = packf(cosf(f * d0));
            r[3 + 6 * l + 4] = packf(cosf(f * d1));
            r[3 + 6 * l + 5] = packf(cosf(f * d2));
            f *= 2.f;
        }
        #pragma unroll
        for (int c = 27; c < 32; ++c) r[c] = 0u;   // zero-pad K 283..287
    }
    __syncthreads();

    const int lane = tid & 63, wv = tid >> 6;
    const int q = lane >> 4, ln = lane & 15;
    const int colbase = wv * 64;
    const float* bb = be + e * 4 * HD;
    const unsigned short* W0 = EWp + (size_t)(e * 4) * 131072;

    unsigned skipv[4][4][4];   // original input, stashed at l0 write phase

    // ---- layer 0: A <- relu(A @ W0 + b0), stash skip ----
    {
        f4 acc[4][4];
        #pragma unroll
        for (int mt = 0; mt < 4; ++mt)
            #pragma unroll
            for (int nl = 0; nl < 4; ++nl) acc[mt][nl] = (f4){0.f, 0.f, 0.f, 0.f};
        gemm_tile<8, 4, 16>(Apk, W0, W0 + 65536, lane, wv * 4, acc);
        __syncthreads();
        #pragma unroll
        for (int nl = 0; nl < 4; ++nl) {
            const int col = colbase + nl * 16 + ln;
            const float bias = bb[col];
            #pragma unroll
            for (int mt = 0; mt < 4; ++mt)
                #pragma unroll
                for (int r = 0; r < 4; ++r) {
                    const int row = mt * 16 + q * 4 + r;
                    unsigned* dst = &Apk[row * STR + col];
                    skipv[nl][mt][r] = *dst;
                    *dst = packf(fmaxf(acc[mt][nl][r] + bias, 0.f));
                }
        }
        __syncthreads();
    }
    // ---- layer 1: A <- relu(A @ W1 + b1 + skip) ----
    {
        f4 acc[4][4];
        #pragma unroll
        for (int mt = 0; mt < 4; ++mt)
            #pragma unroll
            for (int nl = 0; nl < 4; ++nl) acc[mt][nl] = (f4){0.f, 0.f, 0.f, 0.f};
        gemm_tile<8, 4, 16>(Apk, W0 + 131072, W0 + 131072 + 65536, lane, wv * 4, acc);
        __syncthreads();
        #pragma unroll
        for (int nl = 0; nl < 4; ++nl) {
            const int col = colbase + nl * 16 + ln;
            const float bias = bb[256 + col];
            #pragma unroll
            for (int mt = 0; mt < 4; ++mt)
                #pragma unroll
                for (int r = 0; r < 4; ++r) {
                    const int row = mt * 16 + q * 4 + r;
                    const float v = acc[mt][nl][r] + bias + unpackf(skipv[nl][mt][r]);
                    Apk[row * STR + col] = packf(fmaxf(v, 0.f));
                }
        }
        __syncthreads();
    }
    // ---- layer 2: A <- relu(A @ W2 + b2) ----
    {
        f4 acc[4][4];
        #pragma unroll
        for (int mt = 0; mt < 4; ++mt)
            #pragma unroll
            for (int nl = 0; nl < 4; ++nl) acc[mt][nl] = (f4){0.f, 0.f, 0.f, 0.f};
        gemm_tile<8, 4, 16>(Apk, W0 + 2 * 131072, W0 + 2 * 131072 + 65536, lane, wv * 4, acc);
        __syncthreads();
        #pragma unroll
        for (int nl = 0; nl < 4; ++nl) {
            const int col = colbase + nl * 16 + ln;
            const float bias = bb[512 + col];
            #pragma unroll
            for (int mt = 0; mt < 4; ++mt)
                #pragma unroll
                for (int r = 0; r < 4; ++r) {
                    const int row = mt * 16 + q * 4 + r;
                    Apk[row * STR + col] = packf(fmaxf(acc[mt][nl][r] + bias, 0.f));
                }
        }
        __syncthreads();
    }
    // ---- layer 3: A <- gate * (A @ W3 + b3)  (no relu) ----
    {
        f4 acc[4][4];
        #pragma unroll
        for (int mt = 0; mt < 4; ++mt)
            #pragma unroll
            for (int nl = 0; nl < 4; ++nl) acc[mt][nl] = (f4){0.f, 0.f, 0.f, 0.f};
        gemm_tile<8, 4, 16>(Apk, W0 + 3 * 131072, W0 + 3 * 131072 + 65536, lane, wv * 4, acc);
        __syncthreads();
        #pragma unroll
        for (int nl = 0; nl < 4; ++nl) {
            const int col = colbase + nl * 16 + ln;
            const float bias = bb[768 + col];
            #pragma unroll
            for (int mt = 0; mt < 4; ++mt)
                #pragma unroll
                for (int r = 0; r < 4; ++r) {
                    const int row = mt * 16 + q * 4 + r;
                    Apk[row * STR + col] = packf(gatev[row] * (acc[mt][nl][r] + bias));
                }
        }
        __syncthreads();
    }

    // ---- heads: s = relu(out@Ws1+bs1), c = relu([out,ed]@Wc1+bc1) ----
    {
        f4 sacc[4][2], cacc[4][2];
        #pragma unroll
        for (int mt = 0; mt < 4; ++mt)
            #pragma unroll
            for (int nl = 0; nl < 2; ++nl) {
                sacc[mt][nl] = (f4){0.f, 0.f, 0.f, 0.f};
                cacc[mt][nl] = (f4){0.f, 0.f, 0.f, 0.f};
            }
        gemm_tile<8, 2, 8>(Apk, Ws1p, Ws1p + 32768, lane, wv * 2, sacc);
        gemm_tile<9, 2, 8>(Apk, Wc1p, Wc1p + 36864, lane, wv * 2, cacc);
        __syncthreads();
        #pragma unroll
        for (int nl = 0; nl < 2; ++nl) {
            const int col = wv * 32 + nl * 16 + ln;
            const float b_s = bs1[col], b_c = bc1[col];
            #pragma unroll
            for (int mt = 0; mt < 4; ++mt)
                #pragma unroll
                for (int r = 0; r < 4; ++r) {
                    const int row = mt * 16 + q * 4 + r;
                    Apk[row * STR + col]       = packf(fmaxf(sacc[mt][nl][r] + b_s, 0.f));
                    Apk[row * STR + 128 + col] = packf(fmaxf(cacc[mt][nl][r] + b_c, 0.f));
                }
        }
        __syncthreads();
    }
    // ---- final dots (4-way split over k), then reduce + activations ----
    {
        const int row = tid & 63, seg = tid >> 6, k0 = seg * 32;
        float ps = 0.f, p0 = 0.f, p1 = 0.f, p2 = 0.f;
        for (int k = k0; k < k0 + 32; ++k) {
            ps = fmaf(unpackf(Apk[row * STR + k]), Ws2[k], ps);
            const float cv = unpackf(Apk[row * STR + 128 + k]);
            p0 = fmaf(cv, Wc2[3 * k + 0], p0);
            p1 = fmaf(cv, Wc2[3 * k + 1], p1);
            p2 = fmaf(cv, Wc2[3 * k + 2], p2);
        }
        unsigned* pr = &Apk[row * STR + 256 + seg * 4];
        pr[0] = __float_as_uint(ps); pr[1] = __float_as_uint(p0);
        pr[2] = __float_as_uint(p1); pr[3] = __float_as_uint(p2);
    }
    __syncthreads();
    if (tid < nact) {
        float sg = bs2[0], r0 = bc2[0], r1 = bc2[1], r2 = bc2[2];
        #pragma unroll
        for (int s2 = 0; s2 < 4; ++s2) {
            const unsigned* pr = &Apk[tid * STR + 256 + s2 * 4];
            sg += __uint_as_float(pr[0]);
            r0 += __uint_as_float(pr[1]);
            r1 += __uint_as_float(pr[2]);
            r2 += __uint_as_float(pr[3]);
        }
        float4 o;
        o.x = 1.f / (1.f + expf(-r0));
        o.y = 1.f / (1.f + expf(-r1));
        o.z = 1.f / (1.f + expf(-r2));
        o.w = fmaxf(sg, 0.f) + log1pf(expf(-fabsf(sg)));   // stable softplus
        *(float4*)&outp[(size_t)idx[tid] * 4] = o;
    }
}

// ---------------------------------------------------------------------------
extern "C" void kernel_launch(void* const* d_in, const int* in_sizes, int n_in,
                              void* d_out, int out_size, void* d_ws, size_t ws_size,
                              hipStream_t stream)
{
    const float* xyz  = (const float*)d_in[0];
    const float* dirs = (const float*)d_in[1];
    const float* W1   = (const float*)d_in[2];
    const float* b1   = (const float*)d_in[3];
    const float* W2   = (const float*)d_in[4];
    const float* b2   = (const float*)d_in[5];
    const float* Wg   = (const float*)d_in[6];
    const float* bg   = (const float*)d_in[7];
    const float* We   = (const float*)d_in[8];
    const float* be   = (const float*)d_in[9];
    const float* Ws1  = (const float*)d_in[10];
    const float* bs1  = (const float*)d_in[11];
    const float* Ws2  = (const float*)d_in[12];
    const float* bs2  = (const float*)d_in[13];
    const float* Wc1  = (const float*)d_in[14];
    const float* bc1  = (const float*)d_in[15];
    const float* Wc2  = (const float*)d_in[16];
    const float* bc2  = (const float*)d_in[17];
    float* out = (float*)d_out;

    char* ws = (char*)d_ws;
    unsigned*       h2p     = (unsigned*)ws;                        // 64 MB packed h2
    float*          gatebuf = (float*)(ws + 67108864);              // 256 KB
    int*            counts  = (int*)(ws + 67371008);                // 1 KB (padded)
    int*            bucket  = (int*)(ws + 67372032);                // 2 MB
    unsigned short* EWp     = (unsigned short*)(ws + 69469184);     // 8 MB expert frags
    unsigned short* Ws1p    = (unsigned short*)(ws + 77857792);     // 128 KB
    unsigned short* Wc1p    = (unsigned short*)(ws + 77988864);     // 144 KB

    hipMemsetAsync(counts, 0, NE * sizeof(int), stream);
    prep_expert<<<1024, 256, 0, stream>>>(We, EWp);
    prep_head<<<16, 256, 0, stream>>>(Ws1, Ws1p, 8, 256);
    prep_head<<<18, 256, 0, stream>>>(Wc1, Wc1p, 9, 283);
    trunk_kernel<<<NS / 64, 256, 0, stream>>>(xyz, W1, b1, W2, b2, Wg, bg,
                                              h2p, gatebuf, counts, bucket);
    expert_kernel<<<NE * 1024, 256, 0, stream>>>(h2p, gatebuf, counts, bucket,
                                                 EWp, be, dirs, Ws1p, bs1, Ws2, bs2,
                                                 Wc1p, bc1, Wc2, bc2, out);
}

// Round 3
// 417.895 us; speedup vs baseline: 2.8262x; 1.1682x over previous
//
#include <hip/hip_runtime.h>
#include <math.h>

#define NS 65536
#define HD 256
#define NE 8
#define STR 292   // expert Apk row stride in uint32

typedef short bh8 __attribute__((ext_vector_type(8)));   // 8 bf16 (A/B frag)
typedef float f4  __attribute__((ext_vector_type(4)));   // MFMA acc

// ---------------------------------------------------------------------------
// split-bf16 helpers
// ---------------------------------------------------------------------------
__device__ __forceinline__ unsigned packf(float x) {
    unsigned u  = __float_as_uint(x);
    unsigned hb = (u + 0x7fffu + ((u >> 16) & 1u)) & 0xffff0000u;
    float    lo = x - __uint_as_float(hb);
    unsigned ul = __float_as_uint(lo);
    unsigned lb = (ul + 0x7fffu + ((ul >> 16) & 1u)) >> 16;
    return (hb >> 16) | (lb << 16);
}
__device__ __forceinline__ float unpackf(unsigned p) {
    return __uint_as_float(p << 16) + __uint_as_float(p & 0xffff0000u);
}
__device__ __forceinline__ void bfsplit(float x, unsigned short& h, unsigned short& l) {
    unsigned u  = __float_as_uint(x);
    unsigned hb = (u + 0x7fffu + ((u >> 16) & 1u)) & 0xffff0000u;
    h = (unsigned short)(hb >> 16);
    float    lo = x - __uint_as_float(hb);
    unsigned ul = __float_as_uint(lo);
    l = (unsigned short)((ul + 0x7fffu + ((ul >> 16) & 1u)) >> 16);
}
// 3-way split: x = hi + mid + lo, residual ~2^-26 |x|
__device__ __forceinline__ void bfsplit3(float x, unsigned short& h,
                                         unsigned short& m, unsigned short& l) {
    unsigned u  = __float_as_uint(x);
    unsigned hb = (u + 0x7fffu + ((u >> 16) & 1u)) & 0xffff0000u;
    h = (unsigned short)(hb >> 16);
    float r1 = x - __uint_as_float(hb);
    unsigned u1 = __float_as_uint(r1);
    unsigned mb = (u1 + 0x7fffu + ((u1 >> 16) & 1u)) & 0xffff0000u;
    m = (unsigned short)(mb >> 16);
    float r2 = r1 - __uint_as_float(mb);
    unsigned u2 = __float_as_uint(r2);
    l = (unsigned short)((u2 + 0x7fffu + ((u2 >> 16) & 1u)) >> 16);
}

// 8 packed uint32 -> hi-plane short8 + lo-plane short8 (expert path)
__device__ __forceinline__ void unpack8(const unsigned* p, bh8& h, bh8& l) {
    uint4 a = *(const uint4*)p;
    uint4 b = *(const uint4*)(p + 4);
    union { unsigned u[4]; bh8 v; } H, L;
    H.u[0] = __builtin_amdgcn_perm(a.y, a.x, 0x05040100u);
    H.u[1] = __builtin_amdgcn_perm(a.w, a.z, 0x05040100u);
    H.u[2] = __builtin_amdgcn_perm(b.y, b.x, 0x05040100u);
    H.u[3] = __builtin_amdgcn_perm(b.w, b.z, 0x05040100u);
    L.u[0] = __builtin_amdgcn_perm(a.y, a.x, 0x07060302u);
    L.u[1] = __builtin_amdgcn_perm(a.w, a.z, 0x07060302u);
    L.u[2] = __builtin_amdgcn_perm(b.y, b.x, 0x07060302u);
    L.u[3] = __builtin_amdgcn_perm(b.w, b.z, 0x07060302u);
    h = H.v; l = L.v;
}

// ---------------------------------------------------------------------------
// Expert-side MFMA tile GEMM (2-way split, 3 terms) — unchanged from R2
// ---------------------------------------------------------------------------
template<int KC, int NTW, int NT>
__device__ __forceinline__ void gemm_tile(const unsigned* __restrict__ Apk,
                                          const unsigned short* __restrict__ Wh,
                                          const unsigned short* __restrict__ Wl,
                                          int lane, int ntoff, f4 acc[4][NTW])
{
    const int q = lane >> 4, m = lane & 15;
    for (int kc = 0; kc < KC; ++kc) {
        bh8 ah[4], al[4];
        #pragma unroll
        for (int mt = 0; mt < 4; ++mt)
            unpack8(Apk + (mt * 16 + m) * STR + kc * 32 + q * 8, ah[mt], al[mt]);
        #pragma unroll
        for (int nl = 0; nl < NTW; ++nl) {
            const int fo = ((kc * NT + (ntoff + nl)) * 64 + lane) * 8;
            const bh8 bh = *(const bh8*)(Wh + fo);
            const bh8 bl = *(const bh8*)(Wl + fo);
            #pragma unroll
            for (int mt = 0; mt < 4; ++mt) {
                acc[mt][nl] = __builtin_amdgcn_mfma_f32_16x16x32_bf16(ah[mt], bh, acc[mt][nl], 0, 0, 0);
                acc[mt][nl] = __builtin_amdgcn_mfma_f32_16x16x32_bf16(al[mt], bh, acc[mt][nl], 0, 0, 0);
                acc[mt][nl] = __builtin_amdgcn_mfma_f32_16x16x32_bf16(ah[mt], bl, acc[mt][nl], 0, 0, 0);
            }
        }
    }
}

// ---------------------------------------------------------------------------
// Trunk-side MFMA GEMM: 3-plane A (LDS, A-frag layout) x 3-plane W (global,
// B-frag layout), 6 terms, small->large for accuracy. 64 rows, NT=16.
// A-frag elem offset: ((kc*4+mt)*4+q)*128 + m*8 ; plane stride KC*2048.
// W-frag elem offset: ((kc*16+nt)*64+lane)*8  ; plane stride KC*8192.
// ---------------------------------------------------------------------------
template<int KC>
__device__ __forceinline__ void gemm3(const unsigned short* __restrict__ Ap,
                                      const unsigned short* __restrict__ Wp,
                                      int lane, int ntoff, f4 acc[4][4])
{
    const int q = lane >> 4, m = lane & 15;
    const int APL = KC * 2048;
    const int WPL = KC * 8192;
    for (int kc = 0; kc < KC; ++kc) {
        bh8 ah[4], am[4], al[4];
        #pragma unroll
        for (int mt = 0; mt < 4; ++mt) {
            const int off = ((kc * 4 + mt) * 4 + q) * 128 + m * 8;
            ah[mt] = *(const bh8*)(Ap + off);
            am[mt] = *(const bh8*)(Ap + APL + off);
            al[mt] = *(const bh8*)(Ap + 2 * APL + off);
        }
        #pragma unroll
        for (int nl = 0; nl < 4; ++nl) {
            const int fo = ((kc * 16 + (ntoff + nl)) * 64 + lane) * 8;
            const bh8 bh = *(const bh8*)(Wp + fo);
            const bh8 bm = *(const bh8*)(Wp + WPL + fo);
            const bh8 bl = *(const bh8*)(Wp + 2 * WPL + fo);
            #pragma unroll
            for (int mt = 0; mt < 4; ++mt) {
                acc[mt][nl] = __builtin_amdgcn_mfma_f32_16x16x32_bf16(ah[mt], bl, acc[mt][nl], 0, 0, 0);
                acc[mt][nl] = __builtin_amdgcn_mfma_f32_16x16x32_bf16(am[mt], bm, acc[mt][nl], 0, 0, 0);
                acc[mt][nl] = __builtin_amdgcn_mfma_f32_16x16x32_bf16(al[mt], bh, acc[mt][nl], 0, 0, 0);
                acc[mt][nl] = __builtin_amdgcn_mfma_f32_16x16x32_bf16(ah[mt], bm, acc[mt][nl], 0, 0, 0);
                acc[mt][nl] = __builtin_amdgcn_mfma_f32_16x16x32_bf16(am[mt], bh, acc[mt][nl], 0, 0, 0);
                acc[mt][nl] = __builtin_amdgcn_mfma_f32_16x16x32_bf16(ah[mt], bh, acc[mt][nl], 0, 0, 0);
            }
        }
    }
}

// ---------------------------------------------------------------------------
// Weight preps
// ---------------------------------------------------------------------------
__global__ void prep_expert(const float* __restrict__ We, unsigned short* __restrict__ dst) {
    const int gid = blockIdx.x * 256 + threadIdx.x;        // 262144 threads
    const int nn = gid & 15, nt = (gid >> 4) & 15, qd = (gid >> 8) & 3;
    const int kc = (gid >> 10) & 7, el = gid >> 13;        // el = e*4 + l
    const int n = nt * 16 + nn;
    const float* src = We + (size_t)el * 65536 + (size_t)(kc * 32 + qd * 8) * 256 + n;
    union { unsigned short u[8]; bh8 v; } H, L;
    #pragma unroll
    for (int j = 0; j < 8; ++j) bfsplit(src[j * 256], H.u[j], L.u[j]);
    unsigned short* d = dst + (size_t)el * 131072 + (size_t)((kc * 16 + nt) * 64 + qd * 16 + nn) * 8;
    *(bh8*)d = H.v;
    *(bh8*)(d + 65536) = L.v;
}

__global__ void prep_head(const float* __restrict__ W, unsigned short* __restrict__ dst,
                          int KC, int Kreal) {
    const int gid = blockIdx.x * 256 + threadIdx.x;
    if (gid >= KC * 512) return;
    const int nn = gid & 15, nt = (gid >> 4) & 7, qd = (gid >> 7) & 3, kc = gid >> 9;
    const int n = nt * 16 + nn;
    union { unsigned short u[8]; bh8 v; } H, L;
    #pragma unroll
    for (int j = 0; j < 8; ++j) {
        const int k = kc * 32 + qd * 8 + j;
        const float x = (k < Kreal) ? W[k * 128 + n] : 0.f;
        bfsplit(x, H.u[j], L.u[j]);
    }
    unsigned short* d = dst + (size_t)((kc * 8 + nt) * 64 + qd * 16 + nn) * 8;
    *(bh8*)d = H.v;
    *(bh8*)(d + KC * 4096) = L.v;
}

// 3-plane B-frag prep for trunk weights (ldw = 256, N = 256, NT = 16)
__global__ void prep_trunk3(const float* __restrict__ W, unsigned short* __restrict__ dst,
                            int KC, int Kreal) {
    const int gid = blockIdx.x * 256 + threadIdx.x;
    if (gid >= KC * 1024) return;
    const int n15 = gid & 15, qd = (gid >> 4) & 3, nt = (gid >> 6) & 15, kc = gid >> 10;
    const int n = nt * 16 + n15;
    const int plane = KC * 8192;
    union { unsigned short u[8]; bh8 v; } H, M, L;
    #pragma unroll
    for (int j = 0; j < 8; ++j) {
        const int k = kc * 32 + qd * 8 + j;
        const float x = (k < Kreal) ? W[k * 256 + n] : 0.f;
        bfsplit3(x, H.u[j], M.u[j], L.u[j]);
    }
    unsigned short* d = dst + (size_t)gid * 8;
    *(bh8*)d = H.v;
    *(bh8*)(d + plane) = M.v;
    *(bh8*)(d + 2 * plane) = L.v;
}

// ---------------------------------------------------------------------------
// Kernel 1: posenc -> l1 (MFMA) -> l2 (MFMA) -> gate (fp32) + bucket.
// 64 rows / block, 256 threads (4 waves partition the 256 output cols).
// ---------------------------------------------------------------------------
__global__ __launch_bounds__(256, 1) void trunk_kernel(
    const float* __restrict__ xyz,
    const unsigned short* __restrict__ W1p, const float* __restrict__ b1,
    const unsigned short* __restrict__ W2p, const float* __restrict__ b2,
    const float* __restrict__ Wg, const float* __restrict__ bg,
    unsigned* __restrict__ h2p, float* __restrict__ gateout,
    int* __restrict__ counts, int* __restrict__ bucket)
{
    __shared__ unsigned short exP[3 * 4096];    // posenc planes, A-frag layout (KC=2)
    __shared__ unsigned short h1P[3 * 16384];   // h1 planes (KC=8); reused as fp32 h2
    __shared__ int lcount[NE];
    __shared__ int lbase[NE];
    __shared__ int lpos[64];
    __shared__ int lexp[64];

    const int tid  = threadIdx.x;
    const int row0 = blockIdx.x * 64;

    if (tid < NE) lcount[tid] = 0;

    // --- posenc: 256 threads, each row covered by 4 threads (16 k's each) ---
    {
        const int row = tid & 63, g = tid >> 6;
        const int i = row0 + row;
        const float x0 = xyz[3 * i], x1 = xyz[3 * i + 1], x2 = xyz[3 * i + 2];
        const float xv[3] = {x0, x1, x2};
        const int mt = row >> 4, m = row & 15;
        for (int k = g * 16; k < g * 16 + 16; ++k) {
            float v;
            if (k < 3)       v = xv[k];
            else if (k < 63) {
                const int l = (k - 3) / 6, c = (k - 3) % 6;
                const float f = (float)(1 << l);
                v = (c < 3) ? sinf(f * xv[c]) : cosf(f * xv[c - 3]);
            } else           v = 0.f;
            const int kc = k >> 5, q = (k >> 3) & 3, j = k & 7;
            const int off = ((kc * 4 + mt) * 4 + q) * 128 + m * 8 + j;
            unsigned short h, md, l2v;
            bfsplit3(v, h, md, l2v);
            exP[off] = h; exP[4096 + off] = md; exP[8192 + off] = l2v;
        }
    }
    __syncthreads();

    const int lane = tid & 63, wv = tid >> 6;
    const int q = lane >> 4, n15 = lane & 15;
    const int colbase = wv * 64;

    // --- l1 = relu(ex @ W1 + b1): MFMA, then split3 into h1 planes ---
    f4 acc[4][4];
    #pragma unroll
    for (int mt = 0; mt < 4; ++mt)
        #pragma unroll
        for (int nl = 0; nl < 4; ++nl) acc[mt][nl] = (f4){0.f, 0.f, 0.f, 0.f};
    gemm3<2>(exP, W1p, lane, wv * 4, acc);
    // (exP and h1P disjoint: no barrier needed before h1 writes)
    #pragma unroll
    for (int nl = 0; nl < 4; ++nl) {
        const int col = colbase + nl * 16 + n15;
        const float bias = b1[col];
        const int kc = col >> 5, q2 = (col >> 3) & 3, j = col & 7;
        #pragma unroll
        for (int mt = 0; mt < 4; ++mt)
            #pragma unroll
            for (int r = 0; r < 4; ++r) {
                const int row = mt * 16 + q * 4 + r;
                const float v = fmaxf(acc[mt][nl][r] + bias, 0.f);
                const int off = ((kc * 4 + (row >> 4)) * 4 + q2) * 128 + (row & 15) * 8 + j;
                unsigned short h, md, l2v;
                bfsplit3(v, h, md, l2v);
                h1P[off] = h; h1P[16384 + off] = md; h1P[32768 + off] = l2v;
            }
    }
    __syncthreads();

    // --- l2 = h1 @ W2 + b2: MFMA ---
    #pragma unroll
    for (int mt = 0; mt < 4; ++mt)
        #pragma unroll
        for (int nl = 0; nl < 4; ++nl) acc[mt][nl] = (f4){0.f, 0.f, 0.f, 0.f};
    gemm3<8>(h1P, W2p, lane, wv * 4, acc);
    __syncthreads();   // all h1 reads done before region reuse

    // --- l2 epilogue: +bias, pack to global h2p, fp32 h2 into LDS (h1P) ---
    float* h2f = (float*)h1P;                       // [64][260]
    #pragma unroll
    for (int nl = 0; nl < 4; ++nl) {
        const int col = colbase + nl * 16 + n15;
        const float bias = b2[col];
        #pragma unroll
        for (int mt = 0; mt < 4; ++mt)
            #pragma unroll
            for (int r = 0; r < 4; ++r) {
                const int row = mt * 16 + q * 4 + r;
                const float v = acc[mt][nl][r] + bias;
                h2p[(size_t)(row0 + row) * HD + col] = packf(v);
                h2f[row * 260 + col] = v;
            }
    }
    __syncthreads();

    // --- gate partials: 4 waves split K; partials into exP region ---
    float* part = (float*)exP;                      // [4][64][8]
    {
        const int row = tid & 63, k0 = wv * 64;
        float lg[NE];
        #pragma unroll
        for (int e = 0; e < NE; ++e) lg[e] = 0.f;
        for (int k = k0; k < k0 + 64; ++k) {
            const float hv = h2f[row * 260 + k];
            const float4 w0 = *(const float4*)(Wg + k * 8);
            const float4 w1 = *(const float4*)(Wg + k * 8 + 4);
            lg[0] = fmaf(hv, w0.x, lg[0]); lg[1] = fmaf(hv, w0.y, lg[1]);
            lg[2] = fmaf(hv, w0.z, lg[2]); lg[3] = fmaf(hv, w0.w, lg[3]);
            lg[4] = fmaf(hv, w1.x, lg[4]); lg[5] = fmaf(hv, w1.y, lg[5]);
            lg[6] = fmaf(hv, w1.z, lg[6]); lg[7] = fmaf(hv, w1.w, lg[7]);
        }
        #pragma unroll
        for (int e = 0; e < NE; ++e) part[(wv * 64 + row) * 8 + e] = lg[e];
    }
    __syncthreads();

    // --- finalize gate: softmax top-1, bucket ---
    if (tid < 64) {
        float lg[NE];
        #pragma unroll
        for (int e = 0; e < NE; ++e)
            lg[e] = bg[e] + part[tid * 8 + e] + part[(64 + tid) * 8 + e]
                  + part[(128 + tid) * 8 + e] + part[(192 + tid) * 8 + e];
        int best = 0; float mx = lg[0];
        #pragma unroll
        for (int e = 1; e < NE; ++e) if (lg[e] > mx) { mx = lg[e]; best = e; }
        float s = 0.f;
        #pragma unroll
        for (int e = 0; e < NE; ++e) s += expf(lg[e] - mx);
        gateout[row0 + tid] = 1.f / s;
        lexp[tid] = best;
        lpos[tid] = atomicAdd(&lcount[best], 1);
    }
    __syncthreads();
    if (tid < NE) lbase[tid] = atomicAdd(&counts[tid], lcount[tid]);
    __syncthreads();
    if (tid < 64) {
        const int e = lexp[tid];
        bucket[e * NS + lbase[e] + lpos[tid]] = row0 + tid;
    }
}

// ---------------------------------------------------------------------------
// Kernel 2: expert MLP + heads (unchanged from R2 — proven)
// ---------------------------------------------------------------------------
__global__ __launch_bounds__(256, 2) void expert_kernel(
    const unsigned* __restrict__ h2p, const float* __restrict__ gatebuf,
    const int* __restrict__ counts, const int* __restrict__ bucket,
    const unsigned short* __restrict__ EWp, const float* __restrict__ be,
    const float* __restrict__ dirs,
    const unsigned short* __restrict__ Ws1p, const float* __restrict__ bs1,
    const float* __restrict__ Ws2, const float* __restrict__ bs2,
    const unsigned short* __restrict__ Wc1p, const float* __restrict__ bc1,
    const float* __restrict__ Wc2, const float* __restrict__ bc2,
    float* __restrict__ outp)
{
    __shared__ unsigned Apk[64 * STR];
    __shared__ int   idx[64];
    __shared__ float gatev[64];

    const int tid = threadIdx.x;
    const int e   = blockIdx.x >> 10;
    const int t   = blockIdx.x & 1023;
    const int cnt = counts[e];
    if (t * 64 >= cnt) return;
    const int nact = min(64, cnt - t * 64);

    if (tid < 64) {
        const int src = bucket[e * NS + t * 64 + min(tid, nact - 1)];
        idx[tid]   = src;
        gatev[tid] = gatebuf[src];
    }
    __syncthreads();

    {
        const int row = tid >> 2, cb = (tid & 3) * 64;
        const unsigned* src = h2p + (size_t)idx[row] * HD + cb;
        #pragma unroll 4
        for (int c = 0; c < 64; c += 4)
            *(uint4*)&Apk[row * STR + cb + c] = *(const uint4*)(src + c);
    }
    if (tid < 64) {
        const int i = idx[tid];
        const float d0 = dirs[3 * i], d1 = dirs[3 * i + 1], d2 = dirs[3 * i + 2];
        unsigned* r = &Apk[tid * STR + 256];
        r[0] = packf(d0); r[1] = packf(d1); r[2] = packf(d2);
        float f = 1.f;
        #pragma unroll
        for (int l = 0; l < 4; ++l) {
            r[3 + 6 * l + 0] = packf(sinf(f * d0));
            r[3 + 6 * l + 1] = packf(sinf(f * d1));
            r[3 + 6 * l + 2] = packf(sinf(f * d2));
            r[3 + 6 * l + 3] = packf(cosf(f * d0));
            r[3 + 6 * l + 4] = packf(cosf(f * d1));
            r[3 + 6 * l + 5] = packf(cosf(f * d2));
            f *= 2.f;
        }
        #pragma unroll
        for (int c = 27; c < 32; ++c) r[c] = 0u;
    }
    __syncthreads();

    const int lane = tid & 63, wv = tid >> 6;
    const int q = lane >> 4, ln = lane & 15;
    const int colbase = wv * 64;
    const float* bb = be + e * 4 * HD;
    const unsigned short* W0 = EWp + (size_t)(e * 4) * 131072;

    unsigned skipv[4][4][4];

    {   // l0
        f4 acc[4][4];
        #pragma unroll
        for (int mt = 0; mt < 4; ++mt)
            #pragma unroll
            for (int nl = 0; nl < 4; ++nl) acc[mt][nl] = (f4){0.f, 0.f, 0.f, 0.f};
        gemm_tile<8, 4, 16>(Apk, W0, W0 + 65536, lane, wv * 4, acc);
        __syncthreads();
        #pragma unroll
        for (int nl = 0; nl < 4; ++nl) {
            const int col = colbase + nl * 16 + ln;
            const float bias = bb[col];
            #pragma unroll
            for (int mt = 0; mt < 4; ++mt)
                #pragma unroll
                for (int r = 0; r < 4; ++r) {
                    const int row = mt * 16 + q * 4 + r;
                    unsigned* dst = &Apk[row * STR + col];
                    skipv[nl][mt][r] = *dst;
                    *dst = packf(fmaxf(acc[mt][nl][r] + bias, 0.f));
                }
        }
        __syncthreads();
    }
    {   // l1 + skip
        f4 acc[4][4];
        #pragma unroll
        for (int mt = 0; mt < 4; ++mt)
            #pragma unroll
            for (int nl = 0; nl < 4; ++nl) acc[mt][nl] = (f4){0.f, 0.f, 0.f, 0.f};
        gemm_tile<8, 4, 16>(Apk, W0 + 131072, W0 + 131072 + 65536, lane, wv * 4, acc);
        __syncthreads();
        #pragma unroll
        for (int nl = 0; nl < 4; ++nl) {
            const int col = colbase + nl * 16 + ln;
            const float bias = bb[256 + col];
            #pragma unroll
            for (int mt = 0; mt < 4; ++mt)
                #pragma unroll
                for (int r = 0; r < 4; ++r) {
                    const int row = mt * 16 + q * 4 + r;
                    const float v = acc[mt][nl][r] + bias + unpackf(skipv[nl][mt][r]);
                    Apk[row * STR + col] = packf(fmaxf(v, 0.f));
                }
        }
        __syncthreads();
    }
    {   // l2
        f4 acc[4][4];
        #pragma unroll
        for (int mt = 0; mt < 4; ++mt)
            #pragma unroll
            for (int nl = 0; nl < 4; ++nl) acc[mt][nl] = (f4){0.f, 0.f, 0.f, 0.f};
        gemm_tile<8, 4, 16>(Apk, W0 + 2 * 131072, W0 + 2 * 131072 + 65536, lane, wv * 4, acc);
        __syncthreads();
        #pragma unroll
        for (int nl = 0; nl < 4; ++nl) {
            const int col = colbase + nl * 16 + ln;
            const float bias = bb[512 + col];
            #pragma unroll
            for (int mt = 0; mt < 4; ++mt)
                #pragma unroll
                for (int r = 0; r < 4; ++r) {
                    const int row = mt * 16 + q * 4 + r;
                    Apk[row * STR + col] = packf(fmaxf(acc[mt][nl][r] + bias, 0.f));
                }
        }
        __syncthreads();
    }
    {   // l3 + gate
        f4 acc[4][4];
        #pragma unroll
        for (int mt = 0; mt < 4; ++mt)
            #pragma unroll
            for (int nl = 0; nl < 4; ++nl) acc[mt][nl] = (f4){0.f, 0.f, 0.f, 0.f};
        gemm_tile<8, 4, 16>(Apk, W0 + 3 * 131072, W0 + 3 * 131072 + 65536, lane, wv * 4, acc);
        __syncthreads();
        #pragma unroll
        for (int nl = 0; nl < 4; ++nl) {
            const int col = colbase + nl * 16 + ln;
            const float bias = bb[768 + col];
            #pragma unroll
            for (int mt = 0; mt < 4; ++mt)
                #pragma unroll
                for (int r = 0; r < 4; ++r) {
                    const int row = mt * 16 + q * 4 + r;
                    Apk[row * STR + col] = packf(gatev[row] * (acc[mt][nl][r] + bias));
                }
        }
        __syncthreads();
    }

    {   // heads
        f4 sacc[4][2], cacc[4][2];
        #pragma unroll
        for (int mt = 0; mt < 4; ++mt)
            #pragma unroll
            for (int nl = 0; nl < 2; ++nl) {
                sacc[mt][nl] = (f4){0.f, 0.f, 0.f, 0.f};
                cacc[mt][nl] = (f4){0.f, 0.f, 0.f, 0.f};
            }
        gemm_tile<8, 2, 8>(Apk, Ws1p, Ws1p + 32768, lane, wv * 2, sacc);
        gemm_tile<9, 2, 8>(Apk, Wc1p, Wc1p + 36864, lane, wv * 2, cacc);
        __syncthreads();
        #pragma unroll
        for (int nl = 0; nl < 2; ++nl) {
            const int col = wv * 32 + nl * 16 + ln;
            const float b_s = bs1[col], b_c = bc1[col];
            #pragma unroll
            for (int mt = 0; mt < 4; ++mt)
                #pragma unroll
                for (int r = 0; r < 4; ++r) {
                    const int row = mt * 16 + q * 4 + r;
                    Apk[row * STR + col]       = packf(fmaxf(sacc[mt][nl][r] + b_s, 0.f));
                    Apk[row * STR + 128 + col] = packf(fmaxf(cacc[mt][nl][r] + b_c, 0.f));
                }
        }
        __syncthreads();
    }
    {   // final dots
        const int row = tid & 63, seg = tid >> 6, k0 = seg * 32;
        float ps = 0.f, p0 = 0.f, p1 = 0.f, p2 = 0.f;
        for (int k = k0; k < k0 + 32; ++k) {
            ps = fmaf(unpackf(Apk[row * STR + k]), Ws2[k], ps);
            const float cv = unpackf(Apk[row * STR + 128 + k]);
            p0 = fmaf(cv, Wc2[3 * k + 0], p0);
            p1 = fmaf(cv, Wc2[3 * k + 1], p1);
            p2 = fmaf(cv, Wc2[3 * k + 2], p2);
        }
        unsigned* pr = &Apk[row * STR + 256 + seg * 4];
        pr[0] = __float_as_uint(ps); pr[1] = __float_as_uint(p0);
        pr[2] = __float_as_uint(p1); pr[3] = __float_as_uint(p2);
    }
    __syncthreads();
    if (tid < nact) {
        float sg = bs2[0], r0 = bc2[0], r1 = bc2[1], r2 = bc2[2];
        #pragma unroll
        for (int s2 = 0; s2 < 4; ++s2) {
            const unsigned* pr = &Apk[tid * STR + 256 + s2 * 4];
            sg += __uint_as_float(pr[0]);
            r0 += __uint_as_float(pr[1]);
            r1 += __uint_as_float(pr[2]);
            r2 += __uint_as_float(pr[3]);
        }
        float4 o;
        o.x = 1.f / (1.f + expf(-r0));
        o.y = 1.f / (1.f + expf(-r1));
        o.z = 1.f / (1.f + expf(-r2));
        o.w = fmaxf(sg, 0.f) + log1pf(expf(-fabsf(sg)));
        *(float4*)&outp[(size_t)idx[tid] * 4] = o;
    }
}

// ---------------------------------------------------------------------------
extern "C" void kernel_launch(void* const* d_in, const int* in_sizes, int n_in,
                              void* d_out, int out_size, void* d_ws, size_t ws_size,
                              hipStream_t stream)
{
    const float* xyz  = (const float*)d_in[0];
    const float* dirs = (const float*)d_in[1];
    const float* W1   = (const float*)d_in[2];
    const float* b1   = (const float*)d_in[3];
    const float* W2   = (const float*)d_in[4];
    const float* b2   = (const float*)d_in[5];
    const float* Wg   = (const float*)d_in[6];
    const float* bg   = (const float*)d_in[7];
    const float* We   = (const float*)d_in[8];
    const float* be   = (const float*)d_in[9];
    const float* Ws1  = (const float*)d_in[10];
    const float* bs1  = (const float*)d_in[11];
    const float* Ws2  = (const float*)d_in[12];
    const float* bs2  = (const float*)d_in[13];
    const float* Wc1  = (const float*)d_in[14];
    const float* bc1  = (const float*)d_in[15];
    const float* Wc2  = (const float*)d_in[16];
    const float* bc2  = (const float*)d_in[17];
    float* out = (float*)d_out;

    char* ws = (char*)d_ws;
    unsigned*       h2p     = (unsigned*)ws;                        // 64 MB packed h2
    float*          gatebuf = (float*)(ws + 67108864);              // 256 KB
    int*            counts  = (int*)(ws + 67371008);                // 1 KB (padded)
    int*            bucket  = (int*)(ws + 67372032);                // 2 MB
    unsigned short* EWp     = (unsigned short*)(ws + 69469184);     // 8 MB expert frags
    unsigned short* Ws1p    = (unsigned short*)(ws + 77857792);     // 128 KB
    unsigned short* Wc1p    = (unsigned short*)(ws + 77988864);     // 144 KB
    unsigned short* W1p     = (unsigned short*)(ws + 78136320);     // 96 KB  (3 planes)
    unsigned short* W2p     = (unsigned short*)(ws + 78234624);     // 384 KB (3 planes)

    hipMemsetAsync(counts, 0, NE * sizeof(int), stream);
    prep_expert<<<1024, 256, 0, stream>>>(We, EWp);
    prep_head<<<16, 256, 0, stream>>>(Ws1, Ws1p, 8, 256);
    prep_head<<<18, 256, 0, stream>>>(Wc1, Wc1p, 9, 283);
    prep_trunk3<<<8, 256, 0, stream>>>(W1, W1p, 2, 63);
    prep_trunk3<<<32, 256, 0, stream>>>(W2, W2p, 8, 256);
    trunk_kernel<<<NS / 64, 256, 0, stream>>>(xyz, W1p, b1, W2p, b2, Wg, bg,
                                              h2p, gatebuf, counts, bucket);
    expert_kernel<<<NE * 1024, 256, 0, stream>>>(h2p, gatebuf, counts, bucket,
                                                 EWp, be, dirs, Ws1p, bs1, Ws2, bs2,
                                                 Wc1p, bc1, Wc2, bc2, out);
}

// Round 4
// 365.141 us; speedup vs baseline: 3.2345x; 1.1445x over previous
//
#include <hip/hip_runtime.h>
#include <math.h>

#define NS 65536
#define HD 256
#define NE 8

typedef short bh8 __attribute__((ext_vector_type(8)));   // 8 bf16 (A/B frag)
typedef float f4  __attribute__((ext_vector_type(4)));   // MFMA acc
typedef unsigned short ush;

// ---------------------------------------------------------------------------
// split helpers. Truncate-hi (residual exact) + RNE-lo: err <= 2^-17|x| (2-way),
// 2^-25|x| (3-way).
// ---------------------------------------------------------------------------
__device__ __forceinline__ void split2t(float x, ush& h, ush& l) {
    unsigned u = __float_as_uint(x);
    h = (ush)(u >> 16);
    float lo = x - __uint_as_float(u & 0xffff0000u);
    unsigned ul = __float_as_uint(lo);
    l = (ush)((ul + 0x7fffu + ((ul >> 16) & 1u)) >> 16);
}
__device__ __forceinline__ unsigned pack2t(float x) {     // hi | lo<<16
    ush h, l; split2t(x, h, l);
    return (unsigned)h | ((unsigned)l << 16);
}
__device__ __forceinline__ void split3t(float x, ush& h, ush& m, ush& l) {
    unsigned u = __float_as_uint(x);
    h = (ush)(u >> 16);
    float r1 = x - __uint_as_float(u & 0xffff0000u);
    unsigned u1 = __float_as_uint(r1);
    m = (ush)(u1 >> 16);
    float r2 = r1 - __uint_as_float(u1 & 0xffff0000u);
    unsigned u2 = __float_as_uint(r2);
    l = (ush)((u2 + 0x7fffu + ((u2 >> 16) & 1u)) >> 16);
}
// RNE 2/3-way splits for the one-time weight preps (slightly tighter)
__device__ __forceinline__ void bfsplit(float x, ush& h, ush& l) {
    unsigned u  = __float_as_uint(x);
    unsigned hb = (u + 0x7fffu + ((u >> 16) & 1u)) & 0xffff0000u;
    h = (ush)(hb >> 16);
    float    lo = x - __uint_as_float(hb);
    unsigned ul = __float_as_uint(lo);
    l = (ush)((ul + 0x7fffu + ((ul >> 16) & 1u)) >> 16);
}
__device__ __forceinline__ void bfsplit3(float x, ush& h, ush& m, ush& l) {
    unsigned u  = __float_as_uint(x);
    unsigned hb = (u + 0x7fffu + ((u >> 16) & 1u)) & 0xffff0000u;
    h = (ush)(hb >> 16);
    float r1 = x - __uint_as_float(hb);
    unsigned u1 = __float_as_uint(r1);
    unsigned mb = (u1 + 0x7fffu + ((u1 >> 16) & 1u)) & 0xffff0000u;
    m = (ush)(mb >> 16);
    float r2 = r1 - __uint_as_float(mb);
    unsigned u2 = __float_as_uint(r2);
    l = (ush)((u2 + 0x7fffu + ((u2 >> 16) & 1u)) >> 16);
}

// 8 packed uint32 -> hi/lo bh8 planes (used once at expert gather)
__device__ __forceinline__ void unpack8(const unsigned* p, bh8& h, bh8& l) {
    uint4 a = *(const uint4*)p;
    uint4 b = *(const uint4*)(p + 4);
    union { unsigned u[4]; bh8 v; } H, L;
    H.u[0] = __builtin_amdgcn_perm(a.y, a.x, 0x05040100u);
    H.u[1] = __builtin_amdgcn_perm(a.w, a.z, 0x05040100u);
    H.u[2] = __builtin_amdgcn_perm(b.y, b.x, 0x05040100u);
    H.u[3] = __builtin_amdgcn_perm(b.w, b.z, 0x05040100u);
    L.u[0] = __builtin_amdgcn_perm(a.y, a.x, 0x07060302u);
    L.u[1] = __builtin_amdgcn_perm(a.w, a.z, 0x07060302u);
    L.u[2] = __builtin_amdgcn_perm(b.y, b.x, 0x07060302u);
    L.u[3] = __builtin_amdgcn_perm(b.w, b.z, 0x07060302u);
    h = H.v; l = L.v;
}

// ---------------------------------------------------------------------------
// 2-plane MFMA GEMM (expert). A planes in LDS A-frag layout:
// off(row,k) = ((kc*MT + row/16)*4 + (k>>3)&3)*128 + (row&15)*8 + (k&7)
// -> contiguous-permutation b128 reads (conflict-free, no v_perm).
// W planes prepped in B-frag order, streamed from L2.
// ---------------------------------------------------------------------------
template<int KC, int NTW, int NT, int MT>
__device__ __forceinline__ void gemm2p(const ush* __restrict__ Ah, const ush* __restrict__ Al,
                                       const ush* __restrict__ Wh, const ush* __restrict__ Wl,
                                       int lane, int ntoff, f4 acc[MT][NTW])
{
    const int q = lane >> 4, m = lane & 15;
    for (int kc = 0; kc < KC; ++kc) {
        bh8 ah[MT], al[MT];
        #pragma unroll
        for (int mt = 0; mt < MT; ++mt) {
            const int off = ((kc * MT + mt) * 4 + q) * 128 + m * 8;
            ah[mt] = *(const bh8*)(Ah + off);
            al[mt] = *(const bh8*)(Al + off);
        }
        #pragma unroll
        for (int nl = 0; nl < NTW; ++nl) {
            const int fo = ((kc * NT + ntoff + nl) * 64 + lane) * 8;
            const bh8 bh = *(const bh8*)(Wh + fo);
            const bh8 bl = *(const bh8*)(Wl + fo);
            #pragma unroll
            for (int mt = 0; mt < MT; ++mt) {
                acc[mt][nl] = __builtin_amdgcn_mfma_f32_16x16x32_bf16(al[mt], bh, acc[mt][nl], 0, 0, 0);
                acc[mt][nl] = __builtin_amdgcn_mfma_f32_16x16x32_bf16(ah[mt], bl, acc[mt][nl], 0, 0, 0);
                acc[mt][nl] = __builtin_amdgcn_mfma_f32_16x16x32_bf16(ah[mt], bh, acc[mt][nl], 0, 0, 0);
            }
        }
    }
}

// 3-plane MFMA GEMM (trunk, gate-accuracy). A planes packed in one LDS array
// (plane stride KC*MT*512); W planes stride KC*8192; NT = 16.
template<int KC, int NTW, int MT>
__device__ __forceinline__ void gemm3(const ush* __restrict__ Ap, const ush* __restrict__ Wp,
                                      int lane, int ntoff, f4 acc[MT][NTW])
{
    const int q = lane >> 4, m = lane & 15;
    const int APL = KC * MT * 512;
    const int WPL = KC * 8192;
    for (int kc = 0; kc < KC; ++kc) {
        bh8 ah[MT], am[MT], al[MT];
        #pragma unroll
        for (int mt = 0; mt < MT; ++mt) {
            const int off = ((kc * MT + mt) * 4 + q) * 128 + m * 8;
            ah[mt] = *(const bh8*)(Ap + off);
            am[mt] = *(const bh8*)(Ap + APL + off);
            al[mt] = *(const bh8*)(Ap + 2 * APL + off);
        }
        #pragma unroll
        for (int nl = 0; nl < NTW; ++nl) {
            const int fo = ((kc * 16 + ntoff + nl) * 64 + lane) * 8;
            const bh8 bh = *(const bh8*)(Wp + fo);
            const bh8 bm = *(const bh8*)(Wp + WPL + fo);
            const bh8 bl = *(const bh8*)(Wp + 2 * WPL + fo);
            #pragma unroll
            for (int mt = 0; mt < MT; ++mt) {
                acc[mt][nl] = __builtin_amdgcn_mfma_f32_16x16x32_bf16(ah[mt], bl, acc[mt][nl], 0, 0, 0);
                acc[mt][nl] = __builtin_amdgcn_mfma_f32_16x16x32_bf16(am[mt], bm, acc[mt][nl], 0, 0, 0);
                acc[mt][nl] = __builtin_amdgcn_mfma_f32_16x16x32_bf16(al[mt], bh, acc[mt][nl], 0, 0, 0);
                acc[mt][nl] = __builtin_amdgcn_mfma_f32_16x16x32_bf16(ah[mt], bm, acc[mt][nl], 0, 0, 0);
                acc[mt][nl] = __builtin_amdgcn_mfma_f32_16x16x32_bf16(am[mt], bh, acc[mt][nl], 0, 0, 0);
                acc[mt][nl] = __builtin_amdgcn_mfma_f32_16x16x32_bf16(ah[mt], bh, acc[mt][nl], 0, 0, 0);
            }
        }
    }
}

// ---------------------------------------------------------------------------
// Weight preps (unchanged formats from R3)
// ---------------------------------------------------------------------------
__global__ void prep_expert(const float* __restrict__ We, ush* __restrict__ dst) {
    const int gid = blockIdx.x * 256 + threadIdx.x;        // 262144 threads
    const int nn = gid & 15, nt = (gid >> 4) & 15, qd = (gid >> 8) & 3;
    const int kc = (gid >> 10) & 7, el = gid >> 13;        // el = e*4 + l
    const int n = nt * 16 + nn;
    const float* src = We + (size_t)el * 65536 + (size_t)(kc * 32 + qd * 8) * 256 + n;
    union { ush u[8]; bh8 v; } H, L;
    #pragma unroll
    for (int j = 0; j < 8; ++j) bfsplit(src[j * 256], H.u[j], L.u[j]);
    ush* d = dst + (size_t)el * 131072 + (size_t)((kc * 16 + nt) * 64 + qd * 16 + nn) * 8;
    *(bh8*)d = H.v;
    *(bh8*)(d + 65536) = L.v;
}

__global__ void prep_head(const float* __restrict__ W, ush* __restrict__ dst,
                          int KC, int Kreal) {
    const int gid = blockIdx.x * 256 + threadIdx.x;
    if (gid >= KC * 512) return;
    const int nn = gid & 15, nt = (gid >> 4) & 7, qd = (gid >> 7) & 3, kc = gid >> 9;
    const int n = nt * 16 + nn;
    union { ush u[8]; bh8 v; } H, L;
    #pragma unroll
    for (int j = 0; j < 8; ++j) {
        const int k = kc * 32 + qd * 8 + j;
        const float x = (k < Kreal) ? W[k * 128 + n] : 0.f;
        bfsplit(x, H.u[j], L.u[j]);
    }
    ush* d = dst + (size_t)((kc * 8 + nt) * 64 + qd * 16 + nn) * 8;
    *(bh8*)d = H.v;
    *(bh8*)(d + KC * 4096) = L.v;
}

__global__ void prep_trunk3(const float* __restrict__ W, ush* __restrict__ dst,
                            int KC, int Kreal) {
    const int gid = blockIdx.x * 256 + threadIdx.x;
    if (gid >= KC * 1024) return;
    const int n15 = gid & 15, qd = (gid >> 4) & 3, nt = (gid >> 6) & 15, kc = gid >> 10;
    const int n = nt * 16 + n15;
    const int plane = KC * 8192;
    union { ush u[8]; bh8 v; } H, M, L;
    #pragma unroll
    for (int j = 0; j < 8; ++j) {
        const int k = kc * 32 + qd * 8 + j;
        const float x = (k < Kreal) ? W[k * 256 + n] : 0.f;
        bfsplit3(x, H.u[j], M.u[j], L.u[j]);
    }
    ush* d = dst + (size_t)gid * 8;
    *(bh8*)d = H.v;
    *(bh8*)(d + plane) = M.v;
    *(bh8*)(d + 2 * plane) = L.v;
}

// ---------------------------------------------------------------------------
// Kernel 1: posenc -> l1 (MFMA) -> l2 (MFMA) -> gate (fp32) + bucket.
// 32 rows / block, 512 threads (8 waves x NTW=2). LDS 61KB -> 2 blocks/CU.
// ---------------------------------------------------------------------------
__global__ __launch_bounds__(512, 4) void trunk_kernel(
    const float* __restrict__ xyz,
    const ush* __restrict__ W1p, const float* __restrict__ b1,
    const ush* __restrict__ W2p, const float* __restrict__ b2,
    const float* __restrict__ Wg, const float* __restrict__ bg,
    unsigned* __restrict__ h2p, float* __restrict__ gateout,
    int* __restrict__ counts, int* __restrict__ bucket)
{
    __shared__ ush exP[3 * 2048];   // posenc planes (KC=2, MT=2); later gate partials
    __shared__ ush h1P[3 * 8192];   // h1 planes (KC=8, MT=2); later fp32 h2
    __shared__ int lcount[NE], lbase[NE], lpos[32], lexp[32];

    const int tid  = threadIdx.x;
    const int row0 = blockIdx.x * 32;
    if (tid < NE) lcount[tid] = 0;

    {   // posenc: thread (row, g) writes 4 k's
        const int row = tid & 31, g = tid >> 5;
        const int i = row0 + row;
        const float xv[3] = {xyz[3 * i], xyz[3 * i + 1], xyz[3 * i + 2]};
        const int mt = row >> 4, m = row & 15;
        #pragma unroll
        for (int kk = 0; kk < 4; ++kk) {
            const int k = g * 4 + kk;
            float v = 0.f;
            if (k < 3) v = xv[k];
            else if (k < 63) {
                const int l = (k - 3) / 6, c = (k - 3) % 6;
                const float f = (float)(1 << l);
                v = (c < 3) ? sinf(f * xv[c]) : cosf(f * xv[c - 3]);
            }
            const int kc = k >> 5, qq = (k >> 3) & 3, j = k & 7;
            const int off = ((kc * 2 + mt) * 4 + qq) * 128 + m * 8 + j;
            ush hh, mm, ll; split3t(v, hh, mm, ll);
            exP[off] = hh; exP[2048 + off] = mm; exP[4096 + off] = ll;
        }
    }
    __syncthreads();

    const int lane = tid & 63, wv = tid >> 6;
    const int q = lane >> 4, n15 = lane & 15;

    // --- l1 = relu(ex @ W1 + b1) -> h1 planes ---
    f4 acc[2][2];
    #pragma unroll
    for (int a = 0; a < 2; ++a)
        #pragma unroll
        for (int b_ = 0; b_ < 2; ++b_) acc[a][b_] = (f4){0.f, 0.f, 0.f, 0.f};
    gemm3<2, 2, 2>(exP, W1p, lane, wv * 2, acc);
    #pragma unroll
    for (int nl = 0; nl < 2; ++nl) {
        const int col = wv * 32 + nl * 16 + n15;
        const float bias = b1[col];
        const int kc = col >> 5, qc = (col >> 3) & 3, jc = col & 7;
        #pragma unroll
        for (int mt = 0; mt < 2; ++mt)
            #pragma unroll
            for (int r = 0; r < 4; ++r) {
                const float v = fmaxf(acc[mt][nl][r] + bias, 0.f);
                const int off = ((kc * 2 + mt) * 4 + qc) * 128 + (q * 4 + r) * 8 + jc;
                ush hh, mm, ll; split3t(v, hh, mm, ll);
                h1P[off] = hh; h1P[8192 + off] = mm; h1P[16384 + off] = ll;
            }
    }
    __syncthreads();

    // --- l2 = h1 @ W2 + b2 ---
    #pragma unroll
    for (int a = 0; a < 2; ++a)
        #pragma unroll
        for (int b_ = 0; b_ < 2; ++b_) acc[a][b_] = (f4){0.f, 0.f, 0.f, 0.f};
    gemm3<8, 2, 2>(h1P, W2p, lane, wv * 2, acc);
    __syncthreads();                 // all h1 reads done before overlay

    float* h2f  = (float*)h1P;       // [32][259] (stride 259: conflict-free scalar)
    float* part = (float*)exP;       // [8][32][8] gate partials (exP dead)
    #pragma unroll
    for (int nl = 0; nl < 2; ++nl) {
        const int col = wv * 32 + nl * 16 + n15;
        const float bias = b2[col];
        #pragma unroll
        for (int mt = 0; mt < 2; ++mt)
            #pragma unroll
            for (int r = 0; r < 4; ++r) {
                const int row = mt * 16 + q * 4 + r;
                const float v = acc[mt][nl][r] + bias;
                h2p[(size_t)(row0 + row) * HD + col] = pack2t(v);
                h2f[row * 259 + col] = v;
            }
    }
    __syncthreads();

    // --- gate partials: 8 segs x 32 rows (256 threads), 32 k each ---
    if (tid < 256) {
        const int row = tid & 31, seg = tid >> 5, k0 = seg * 32;
        float lg[NE];
        #pragma unroll
        for (int e = 0; e < NE; ++e) lg[e] = 0.f;
        for (int k = k0; k < k0 + 32; ++k) {
            const float hv = h2f[row * 259 + k];
            const float4 w0 = *(const float4*)(Wg + k * 8);
            const float4 w1 = *(const float4*)(Wg + k * 8 + 4);
            lg[0] = fmaf(hv, w0.x, lg[0]); lg[1] = fmaf(hv, w0.y, lg[1]);
            lg[2] = fmaf(hv, w0.z, lg[2]); lg[3] = fmaf(hv, w0.w, lg[3]);
            lg[4] = fmaf(hv, w1.x, lg[4]); lg[5] = fmaf(hv, w1.y, lg[5]);
            lg[6] = fmaf(hv, w1.z, lg[6]); lg[7] = fmaf(hv, w1.w, lg[7]);
        }
        #pragma unroll
        for (int e = 0; e < NE; ++e) part[(seg * 32 + row) * 8 + e] = lg[e];
    }
    __syncthreads();

    if (tid < 32) {
        float lg[NE];
        #pragma unroll
        for (int e = 0; e < NE; ++e) {
            float s = bg[e];
            #pragma unroll
            for (int sg = 0; sg < 8; ++sg) s += part[(sg * 32 + tid) * 8 + e];
            lg[e] = s;
        }
        int best = 0; float mx = lg[0];
        #pragma unroll
        for (int e = 1; e < NE; ++e) if (lg[e] > mx) { mx = lg[e]; best = e; }
        float s = 0.f;
        #pragma unroll
        for (int e = 0; e < NE; ++e) s += expf(lg[e] - mx);
        gateout[row0 + tid] = 1.f / s;
        lexp[tid] = best;
        lpos[tid] = atomicAdd(&lcount[best], 1);
    }
    __syncthreads();
    if (tid < NE) lbase[tid] = atomicAdd(&counts[tid], lcount[tid]);
    __syncthreads();
    if (tid < 32) {
        const int e = lexp[tid];
        bucket[e * NS + lbase[e] + lpos[tid]] = row0 + tid;
    }
}

// ---------------------------------------------------------------------------
// Kernel 2: expert MLP + heads. 64 rows / block, 512 threads (8 waves, NTW=2).
// A in two bf16 planes, A-frag layout. LDS 78KB -> 2 blocks/CU (16 waves).
// ---------------------------------------------------------------------------
__global__ __launch_bounds__(512, 4) void expert_kernel(
    const unsigned* __restrict__ h2p, const float* __restrict__ gatebuf,
    const int* __restrict__ counts, const int* __restrict__ bucket,
    const ush* __restrict__ EWp, const float* __restrict__ be,
    const float* __restrict__ dirs,
    const ush* __restrict__ Ws1p, const float* __restrict__ bs1,
    const float* __restrict__ Ws2, const float* __restrict__ bs2,
    const ush* __restrict__ Wc1p, const float* __restrict__ bc1,
    const float* __restrict__ Wc2, const float* __restrict__ bc2,
    float* __restrict__ outp)
{
    __shared__ ush   Ah[9 * 2048];      // hi plane (KC=9 incl. dirs ext); later fp32 s
    __shared__ ush   Al[9 * 2048];      // lo plane;                       later fp32 c
    __shared__ float dotp[4 * 64 * 4];
    __shared__ int   idx[64];
    __shared__ float gatev[64];

    const int tid = threadIdx.x;
    const int e   = blockIdx.x >> 10;
    const int t   = blockIdx.x & 1023;
    const int cnt = counts[e];
    if (t * 64 >= cnt) return;
    const int nact = min(64, cnt - t * 64);

    if (tid < 64) {
        const int src = bucket[e * NS + t * 64 + min(tid, nact - 1)];
        idx[tid]   = src;
        gatev[tid] = gatebuf[src];
    }
    __syncthreads();

    const int lane = tid & 63, wv = tid >> 6;
    const int q = lane >> 4, n15 = lane & 15;

    {   // gather: wave wv -> kc=wv, lane = row; unpack packed h2 into planes
        const int row = lane, mt = row >> 4, m = row & 15;
        const unsigned* src = h2p + (size_t)idx[row] * HD + wv * 32;
        #pragma unroll
        for (int sub = 0; sub < 4; ++sub) {
            bh8 hv, lv;
            unpack8(src + sub * 8, hv, lv);
            const int off = ((wv * 4 + mt) * 4 + sub) * 128 + m * 8;
            *(bh8*)(Ah + off) = hv;
            *(bh8*)(Al + off) = lv;
        }
    }
    if (tid < 64) {   // dirs posenc ext -> kc=8 region
        const int row = tid, i = idx[row];
        const int mt = row >> 4, m = row & 15;
        const float d0 = dirs[3 * i], d1 = dirs[3 * i + 1], d2 = dirs[3 * i + 2];
        float vals[32];
        vals[0] = d0; vals[1] = d1; vals[2] = d2;
        float f = 1.f;
        #pragma unroll
        for (int l = 0; l < 4; ++l) {
            vals[3 + 6 * l + 0] = sinf(f * d0);
            vals[3 + 6 * l + 1] = sinf(f * d1);
            vals[3 + 6 * l + 2] = sinf(f * d2);
            vals[3 + 6 * l + 3] = cosf(f * d0);
            vals[3 + 6 * l + 4] = cosf(f * d1);
            vals[3 + 6 * l + 5] = cosf(f * d2);
            f *= 2.f;
        }
        #pragma unroll
        for (int c = 27; c < 32; ++c) vals[c] = 0.f;
        #pragma unroll
        for (int k2 = 0; k2 < 32; ++k2) {
            const int off = ((8 * 4 + mt) * 4 + (k2 >> 3)) * 128 + m * 8 + (k2 & 7);
            ush hh, ll; split2t(vals[k2], hh, ll);
            Ah[off] = hh; Al[off] = ll;
        }
    }
    __syncthreads();

    const float* bb = be + e * 4 * HD;
    const ush* W0 = EWp + (size_t)(e * 4) * 131072;
    unsigned skipv[32];                 // packed (hi<<16)|lo, order [nl][mt][r]

    // ---- l0: A <- relu(A @ W0 + b0), stash skip ----
    {
        f4 acc[4][2];
        #pragma unroll
        for (int mt = 0; mt < 4; ++mt)
            #pragma unroll
            for (int nl = 0; nl < 2; ++nl) acc[mt][nl] = (f4){0.f, 0.f, 0.f, 0.f};
        gemm2p<8, 2, 16, 4>(Ah, Al, W0, W0 + 65536, lane, wv * 2, acc);
        __syncthreads();
        int si = 0;
        #pragma unroll
        for (int nl = 0; nl < 2; ++nl) {
            const int col = wv * 32 + nl * 16 + n15;
            const float bias = bb[col];
            const int kc = col >> 5, qc = (col >> 3) & 3, jc = col & 7;
            #pragma unroll
            for (int mt = 0; mt < 4; ++mt)
                #pragma unroll
                for (int r = 0; r < 4; ++r) {
                    const int off = ((kc * 4 + mt) * 4 + qc) * 128 + (q * 4 + r) * 8 + jc;
                    skipv[si++] = ((unsigned)Ah[off] << 16) | (unsigned)Al[off];
                    const float v = fmaxf(acc[mt][nl][r] + bias, 0.f);
                    ush hh, ll; split2t(v, hh, ll);
                    Ah[off] = hh; Al[off] = ll;
                }
        }
        __syncthreads();
    }
    // ---- l1: A <- relu(A @ W1 + b1 + skip) ----
    {
        f4 acc[4][2];
        #pragma unroll
        for (int mt = 0; mt < 4; ++mt)
            #pragma unroll
            for (int nl = 0; nl < 2; ++nl) acc[mt][nl] = (f4){0.f, 0.f, 0.f, 0.f};
        gemm2p<8, 2, 16, 4>(Ah, Al, W0 + 131072, W0 + 131072 + 65536, lane, wv * 2, acc);
        __syncthreads();
        int si = 0;
        #pragma unroll
        for (int nl = 0; nl < 2; ++nl) {
            const int col = wv * 32 + nl * 16 + n15;
            const float bias = bb[256 + col];
            const int kc = col >> 5, qc = (col >> 3) & 3, jc = col & 7;
            #pragma unroll
            for (int mt = 0; mt < 4; ++mt)
                #pragma unroll
                for (int r = 0; r < 4; ++r) {
                    const int off = ((kc * 4 + mt) * 4 + qc) * 128 + (q * 4 + r) * 8 + jc;
                    const unsigned s = skipv[si++];
                    const float sk = __uint_as_float(s & 0xffff0000u) + __uint_as_float(s << 16);
                    const float v = fmaxf(acc[mt][nl][r] + bias + sk, 0.f);
                    ush hh, ll; split2t(v, hh, ll);
                    Ah[off] = hh; Al[off] = ll;
                }
        }
        __syncthreads();
    }
    // ---- l2: A <- relu(A @ W2 + b2) ----
    {
        f4 acc[4][2];
        #pragma unroll
        for (int mt = 0; mt < 4; ++mt)
            #pragma unroll
            for (int nl = 0; nl < 2; ++nl) acc[mt][nl] = (f4){0.f, 0.f, 0.f, 0.f};
        gemm2p<8, 2, 16, 4>(Ah, Al, W0 + 2 * 131072, W0 + 2 * 131072 + 65536, lane, wv * 2, acc);
        __syncthreads();
        #pragma unroll
        for (int nl = 0; nl < 2; ++nl) {
            const int col = wv * 32 + nl * 16 + n15;
            const float bias = bb[512 + col];
            const int kc = col >> 5, qc = (col >> 3) & 3, jc = col & 7;
            #pragma unroll
            for (int mt = 0; mt < 4; ++mt)
                #pragma unroll
                for (int r = 0; r < 4; ++r) {
                    const int off = ((kc * 4 + mt) * 4 + qc) * 128 + (q * 4 + r) * 8 + jc;
                    const float v = fmaxf(acc[mt][nl][r] + bias, 0.f);
                    ush hh, ll; split2t(v, hh, ll);
                    Ah[off] = hh; Al[off] = ll;
                }
        }
        __syncthreads();
    }
    // ---- l3: A <- gate * (A @ W3 + b3)  (no relu) ----
    {
        f4 acc[4][2];
        #pragma unroll
        for (int mt = 0; mt < 4; ++mt)
            #pragma unroll
            for (int nl = 0; nl < 2; ++nl) acc[mt][nl] = (f4){0.f, 0.f, 0.f, 0.f};
        gemm2p<8, 2, 16, 4>(Ah, Al, W0 + 3 * 131072, W0 + 3 * 131072 + 65536, lane, wv * 2, acc);
        __syncthreads();
        #pragma unroll
        for (int nl = 0; nl < 2; ++nl) {
            const int col = wv * 32 + nl * 16 + n15;
            const float bias = bb[768 + col];
            const int kc = col >> 5, qc = (col >> 3) & 3, jc = col & 7;
            #pragma unroll
            for (int mt = 0; mt < 4; ++mt)
                #pragma unroll
                for (int r = 0; r < 4; ++r) {
                    const int row = mt * 16 + q * 4 + r;
                    const int off = ((kc * 4 + mt) * 4 + qc) * 128 + (q * 4 + r) * 8 + jc;
                    const float v = gatev[row] * (acc[mt][nl][r] + bias);
                    ush hh, ll; split2t(v, hh, ll);
                    Ah[off] = hh; Al[off] = ll;
                }
        }
        __syncthreads();
    }

    // ---- heads: s = relu(out@Ws1+bs1), c = relu([out,ed]@Wc1+bc1) ----
    {
        f4 sacc[4][1], cacc[4][1];
        #pragma unroll
        for (int mt = 0; mt < 4; ++mt) {
            sacc[mt][0] = (f4){0.f, 0.f, 0.f, 0.f};
            cacc[mt][0] = (f4){0.f, 0.f, 0.f, 0.f};
        }
        gemm2p<8, 1, 8, 4>(Ah, Al, Ws1p, Ws1p + 32768, lane, wv, sacc);
        gemm2p<9, 1, 8, 4>(Ah, Al, Wc1p, Wc1p + 36864, lane, wv, cacc);
        __syncthreads();
        float* sp = (float*)Ah;          // [64][133]
        float* cp = (float*)Al;
        const int col = wv * 16 + n15;
        const float b_s = bs1[col], b_c = bc1[col];
        #pragma unroll
        for (int mt = 0; mt < 4; ++mt)
            #pragma unroll
            for (int r = 0; r < 4; ++r) {
                const int row = mt * 16 + q * 4 + r;
                sp[row * 133 + col] = fmaxf(sacc[mt][0][r] + b_s, 0.f);
                cp[row * 133 + col] = fmaxf(cacc[mt][0][r] + b_c, 0.f);
            }
        __syncthreads();
    }
    // ---- final dots: 4 segs x 64 rows, 32 k each ----
    if (tid < 256) {
        const float* sp = (const float*)Ah;
        const float* cp = (const float*)Al;
        const int row = tid & 63, seg = tid >> 6, k0 = seg * 32;
        float ps = 0.f, p0 = 0.f, p1 = 0.f, p2 = 0.f;
        for (int k = k0; k < k0 + 32; ++k) {
            ps = fmaf(sp[row * 133 + k], Ws2[k], ps);
            const float cv = cp[row * 133 + k];
            p0 = fmaf(cv, Wc2[3 * k + 0], p0);
            p1 = fmaf(cv, Wc2[3 * k + 1], p1);
            p2 = fmaf(cv, Wc2[3 * k + 2], p2);
        }
        *(float4*)&dotp[(seg * 64 + row) * 4] = make_float4(ps, p0, p1, p2);
    }
    __syncthreads();
    if (tid < nact) {
        float sg = bs2[0], r0 = bc2[0], r1 = bc2[1], r2 = bc2[2];
        #pragma unroll
        for (int s2 = 0; s2 < 4; ++s2) {
            const float4 pv = *(const float4*)&dotp[(s2 * 64 + tid) * 4];
            sg += pv.x; r0 += pv.y; r1 += pv.z; r2 += pv.w;
        }
        float4 o;
        o.x = 1.f / (1.f + expf(-r0));
        o.y = 1.f / (1.f + expf(-r1));
        o.z = 1.f / (1.f + expf(-r2));
        o.w = fmaxf(sg, 0.f) + log1pf(expf(-fabsf(sg)));
        *(float4*)&outp[(size_t)idx[tid] * 4] = o;
    }
}

// ---------------------------------------------------------------------------
extern "C" void kernel_launch(void* const* d_in, const int* in_sizes, int n_in,
                              void* d_out, int out_size, void* d_ws, size_t ws_size,
                              hipStream_t stream)
{
    const float* xyz  = (const float*)d_in[0];
    const float* dirs = (const float*)d_in[1];
    const float* W1   = (const float*)d_in[2];
    const float* b1   = (const float*)d_in[3];
    const float* W2   = (const float*)d_in[4];
    const float* b2   = (const float*)d_in[5];
    const float* Wg   = (const float*)d_in[6];
    const float* bg   = (const float*)d_in[7];
    const float* We   = (const float*)d_in[8];
    const float* be   = (const float*)d_in[9];
    const float* Ws1  = (const float*)d_in[10];
    const float* bs1  = (const float*)d_in[11];
    const float* Ws2  = (const float*)d_in[12];
    const float* bs2  = (const float*)d_in[13];
    const float* Wc1  = (const float*)d_in[14];
    const float* bc1  = (const float*)d_in[15];
    const float* Wc2  = (const float*)d_in[16];
    const float* bc2  = (const float*)d_in[17];
    float* out = (float*)d_out;

    char* ws = (char*)d_ws;
    unsigned* h2p     = (unsigned*)ws;                        // 64 MB packed h2
    float*    gatebuf = (float*)(ws + 67108864);              // 256 KB
    int*      counts  = (int*)(ws + 67371008);                // 1 KB (padded)
    int*      bucket  = (int*)(ws + 67372032);                // 2 MB
    ush*      EWp     = (ush*)(ws + 69469184);                // 8 MB expert frags
    ush*      Ws1p    = (ush*)(ws + 77857792);                // 128 KB
    ush*      Wc1p    = (ush*)(ws + 77988864);                // 144 KB
    ush*      W1p     = (ush*)(ws + 78136320);                // 96 KB  (3 planes)
    ush*      W2p     = (ush*)(ws + 78234624);                // 384 KB (3 planes)

    hipMemsetAsync(counts, 0, NE * sizeof(int), stream);
    prep_expert<<<1024, 256, 0, stream>>>(We, EWp);
    prep_head<<<16, 256, 0, stream>>>(Ws1, Ws1p, 8, 256);
    prep_head<<<18, 256, 0, stream>>>(Wc1, Wc1p, 9, 283);
    prep_trunk3<<<8, 256, 0, stream>>>(W1, W1p, 2, 63);
    prep_trunk3<<<32, 256, 0, stream>>>(W2, W2p, 8, 256);
    trunk_kernel<<<NS / 32, 512, 0, stream>>>(xyz, W1p, b1, W2p, b2, Wg, bg,
                                              h2p, gatebuf, counts, bucket);
    expert_kernel<<<NE * 1024, 512, 0, stream>>>(h2p, gatebuf, counts, bucket,
                                                 EWp, be, dirs, Ws1p, bs1, Ws2, bs2,
                                                 Wc1p, bc1, Wc2, bc2, out);
}

// Round 5
// 338.448 us; speedup vs baseline: 3.4896x; 1.0789x over previous
//
#include <hip/hip_runtime.h>
#include <math.h>

#define NS 65536
#define HD 256
#define NE 8

typedef short bh8 __attribute__((ext_vector_type(8)));   // 8 bf16 (A/B frag)
typedef float f4  __attribute__((ext_vector_type(4)));   // MFMA acc
typedef unsigned short ush;

// ---------------------------------------------------------------------------
// split helpers. Truncate-hi (residual exact) + RNE-lo: err <= 2^-17|x| (2-way),
// 2^-25|x| (3-way).
// ---------------------------------------------------------------------------
__device__ __forceinline__ void split2t(float x, ush& h, ush& l) {
    unsigned u = __float_as_uint(x);
    h = (ush)(u >> 16);
    float lo = x - __uint_as_float(u & 0xffff0000u);
    unsigned ul = __float_as_uint(lo);
    l = (ush)((ul + 0x7fffu + ((ul >> 16) & 1u)) >> 16);
}
__device__ __forceinline__ unsigned pack2t(float x) {     // hi | lo<<16
    ush h, l; split2t(x, h, l);
    return (unsigned)h | ((unsigned)l << 16);
}
__device__ __forceinline__ float unpackf(unsigned p) {    // inverse of pack2t
    return __uint_as_float(p << 16) + __uint_as_float(p & 0xffff0000u);
}
__device__ __forceinline__ void split3t(float x, ush& h, ush& m, ush& l) {
    unsigned u = __float_as_uint(x);
    h = (ush)(u >> 16);
    float r1 = x - __uint_as_float(u & 0xffff0000u);
    unsigned u1 = __float_as_uint(r1);
    m = (ush)(u1 >> 16);
    float r2 = r1 - __uint_as_float(u1 & 0xffff0000u);
    unsigned u2 = __float_as_uint(r2);
    l = (ush)((u2 + 0x7fffu + ((u2 >> 16) & 1u)) >> 16);
}
// RNE 2/3-way splits for the one-time weight preps (slightly tighter)
__device__ __forceinline__ void bfsplit(float x, ush& h, ush& l) {
    unsigned u  = __float_as_uint(x);
    unsigned hb = (u + 0x7fffu + ((u >> 16) & 1u)) & 0xffff0000u;
    h = (ush)(hb >> 16);
    float    lo = x - __uint_as_float(hb);
    unsigned ul = __float_as_uint(lo);
    l = (ush)((ul + 0x7fffu + ((ul >> 16) & 1u)) >> 16);
}
__device__ __forceinline__ void bfsplit3(float x, ush& h, ush& m, ush& l) {
    unsigned u  = __float_as_uint(x);
    unsigned hb = (u + 0x7fffu + ((u >> 16) & 1u)) & 0xffff0000u;
    h = (ush)(hb >> 16);
    float r1 = x - __uint_as_float(hb);
    unsigned u1 = __float_as_uint(r1);
    unsigned mb = (u1 + 0x7fffu + ((u1 >> 16) & 1u)) & 0xffff0000u;
    m = (ush)(mb >> 16);
    float r2 = r1 - __uint_as_float(mb);
    unsigned u2 = __float_as_uint(r2);
    l = (ush)((u2 + 0x7fffu + ((u2 >> 16) & 1u)) >> 16);
}

// 8 packed uint32 -> hi/lo bh8 planes (used once at expert gather)
__device__ __forceinline__ void unpack8(const unsigned* p, bh8& h, bh8& l) {
    uint4 a = *(const uint4*)p;
    uint4 b = *(const uint4*)(p + 4);
    union { unsigned u[4]; bh8 v; } H, L;
    H.u[0] = __builtin_amdgcn_perm(a.y, a.x, 0x05040100u);
    H.u[1] = __builtin_amdgcn_perm(a.w, a.z, 0x05040100u);
    H.u[2] = __builtin_amdgcn_perm(b.y, b.x, 0x05040100u);
    H.u[3] = __builtin_amdgcn_perm(b.w, b.z, 0x05040100u);
    L.u[0] = __builtin_amdgcn_perm(a.y, a.x, 0x07060302u);
    L.u[1] = __builtin_amdgcn_perm(a.w, a.z, 0x07060302u);
    L.u[2] = __builtin_amdgcn_perm(b.y, b.x, 0x07060302u);
    L.u[3] = __builtin_amdgcn_perm(b.w, b.z, 0x07060302u);
    h = H.v; l = L.v;
}

// ---------------------------------------------------------------------------
// 2-plane MFMA GEMM (expert). A planes in LDS A-frag layout:
// off(row,k) = ((kc*MT + row/16)*4 + (k>>3)&3)*128 + (row&15)*8 + (k&7)
// -> contiguous-permutation b128 reads (conflict-free, no v_perm).
// W planes prepped in B-frag order, streamed from L2.
// ---------------------------------------------------------------------------
template<int KC, int NTW, int NT, int MT>
__device__ __forceinline__ void gemm2p(const ush* __restrict__ Ah, const ush* __restrict__ Al,
                                       const ush* __restrict__ Wh, const ush* __restrict__ Wl,
                                       int lane, int ntoff, f4 acc[MT][NTW])
{
    const int q = lane >> 4, m = lane & 15;
    for (int kc = 0; kc < KC; ++kc) {
        bh8 ah[MT], al[MT];
        #pragma unroll
        for (int mt = 0; mt < MT; ++mt) {
            const int off = ((kc * MT + mt) * 4 + q) * 128 + m * 8;
            ah[mt] = *(const bh8*)(Ah + off);
            al[mt] = *(const bh8*)(Al + off);
        }
        #pragma unroll
        for (int nl = 0; nl < NTW; ++nl) {
            const int fo = ((kc * NT + ntoff + nl) * 64 + lane) * 8;
            const bh8 bh = *(const bh8*)(Wh + fo);
            const bh8 bl = *(const bh8*)(Wl + fo);
            #pragma unroll
            for (int mt = 0; mt < MT; ++mt) {
                acc[mt][nl] = __builtin_amdgcn_mfma_f32_16x16x32_bf16(al[mt], bh, acc[mt][nl], 0, 0, 0);
                acc[mt][nl] = __builtin_amdgcn_mfma_f32_16x16x32_bf16(ah[mt], bl, acc[mt][nl], 0, 0, 0);
                acc[mt][nl] = __builtin_amdgcn_mfma_f32_16x16x32_bf16(ah[mt], bh, acc[mt][nl], 0, 0, 0);
            }
        }
    }
}

// 3-plane MFMA GEMM (trunk, gate-accuracy). A planes packed in one LDS array
// (plane stride KC*MT*512); W planes stride KC*8192; NT = 16.
template<int KC, int NTW, int MT>
__device__ __forceinline__ void gemm3(const ush* __restrict__ Ap, const ush* __restrict__ Wp,
                                      int lane, int ntoff, f4 acc[MT][NTW])
{
    const int q = lane >> 4, m = lane & 15;
    const int APL = KC * MT * 512;
    const int WPL = KC * 8192;
    for (int kc = 0; kc < KC; ++kc) {
        bh8 ah[MT], am[MT], al[MT];
        #pragma unroll
        for (int mt = 0; mt < MT; ++mt) {
            const int off = ((kc * MT + mt) * 4 + q) * 128 + m * 8;
            ah[mt] = *(const bh8*)(Ap + off);
            am[mt] = *(const bh8*)(Ap + APL + off);
            al[mt] = *(const bh8*)(Ap + 2 * APL + off);
        }
        #pragma unroll
        for (int nl = 0; nl < NTW; ++nl) {
            const int fo = ((kc * 16 + ntoff + nl) * 64 + lane) * 8;
            const bh8 bh = *(const bh8*)(Wp + fo);
            const bh8 bm = *(const bh8*)(Wp + WPL + fo);
            const bh8 bl = *(const bh8*)(Wp + 2 * WPL + fo);
            #pragma unroll
            for (int mt = 0; mt < MT; ++mt) {
                acc[mt][nl] = __builtin_amdgcn_mfma_f32_16x16x32_bf16(ah[mt], bl, acc[mt][nl], 0, 0, 0);
                acc[mt][nl] = __builtin_amdgcn_mfma_f32_16x16x32_bf16(am[mt], bm, acc[mt][nl], 0, 0, 0);
                acc[mt][nl] = __builtin_amdgcn_mfma_f32_16x16x32_bf16(al[mt], bh, acc[mt][nl], 0, 0, 0);
                acc[mt][nl] = __builtin_amdgcn_mfma_f32_16x16x32_bf16(ah[mt], bm, acc[mt][nl], 0, 0, 0);
                acc[mt][nl] = __builtin_amdgcn_mfma_f32_16x16x32_bf16(am[mt], bh, acc[mt][nl], 0, 0, 0);
                acc[mt][nl] = __builtin_amdgcn_mfma_f32_16x16x32_bf16(ah[mt], bh, acc[mt][nl], 0, 0, 0);
            }
        }
    }
}

// ---------------------------------------------------------------------------
// Weight preps (unchanged)
// ---------------------------------------------------------------------------
__global__ void prep_expert(const float* __restrict__ We, ush* __restrict__ dst) {
    const int gid = blockIdx.x * 256 + threadIdx.x;        // 262144 threads
    const int nn = gid & 15, nt = (gid >> 4) & 15, qd = (gid >> 8) & 3;
    const int kc = (gid >> 10) & 7, el = gid >> 13;        // el = e*4 + l
    const int n = nt * 16 + nn;
    const float* src = We + (size_t)el * 65536 + (size_t)(kc * 32 + qd * 8) * 256 + n;
    union { ush u[8]; bh8 v; } H, L;
    #pragma unroll
    for (int j = 0; j < 8; ++j) bfsplit(src[j * 256], H.u[j], L.u[j]);
    ush* d = dst + (size_t)el * 131072 + (size_t)((kc * 16 + nt) * 64 + qd * 16 + nn) * 8;
    *(bh8*)d = H.v;
    *(bh8*)(d + 65536) = L.v;
}

__global__ void prep_head(const float* __restrict__ W, ush* __restrict__ dst,
                          int KC, int Kreal) {
    const int gid = blockIdx.x * 256 + threadIdx.x;
    if (gid >= KC * 512) return;
    const int nn = gid & 15, nt = (gid >> 4) & 7, qd = (gid >> 7) & 3, kc = gid >> 9;
    const int n = nt * 16 + nn;
    union { ush u[8]; bh8 v; } H, L;
    #pragma unroll
    for (int j = 0; j < 8; ++j) {
        const int k = kc * 32 + qd * 8 + j;
        const float x = (k < Kreal) ? W[k * 128 + n] : 0.f;
        bfsplit(x, H.u[j], L.u[j]);
    }
    ush* d = dst + (size_t)((kc * 8 + nt) * 64 + qd * 16 + nn) * 8;
    *(bh8*)d = H.v;
    *(bh8*)(d + KC * 4096) = L.v;
}

__global__ void prep_trunk3(const float* __restrict__ W, ush* __restrict__ dst,
                            int KC, int Kreal) {
    const int gid = blockIdx.x * 256 + threadIdx.x;
    if (gid >= KC * 1024) return;
    const int n15 = gid & 15, qd = (gid >> 4) & 3, nt = (gid >> 6) & 15, kc = gid >> 10;
    const int n = nt * 16 + n15;
    const int plane = KC * 8192;
    union { ush u[8]; bh8 v; } H, M, L;
    #pragma unroll
    for (int j = 0; j < 8; ++j) {
        const int k = kc * 32 + qd * 8 + j;
        const float x = (k < Kreal) ? W[k * 256 + n] : 0.f;
        bfsplit3(x, H.u[j], M.u[j], L.u[j]);
    }
    ush* d = dst + (size_t)gid * 8;
    *(bh8*)d = H.v;
    *(bh8*)(d + plane) = M.v;
    *(bh8*)(d + 2 * plane) = L.v;
}

// ---------------------------------------------------------------------------
// Kernel 1: posenc -> l1 (MFMA) -> l2 (MFMA) -> gate (fp32) + bucket.
// 32 rows / block, 512 threads (8 waves x NTW=2). LDS 61KB -> 2 blocks/CU.
// ---------------------------------------------------------------------------
__global__ __launch_bounds__(512, 4) void trunk_kernel(
    const float* __restrict__ xyz,
    const ush* __restrict__ W1p, const float* __restrict__ b1,
    const ush* __restrict__ W2p, const float* __restrict__ b2,
    const float* __restrict__ Wg, const float* __restrict__ bg,
    unsigned* __restrict__ h2p, float* __restrict__ gateout,
    int* __restrict__ counts, int* __restrict__ bucket)
{
    __shared__ ush exP[3 * 2048];   // posenc planes (KC=2, MT=2); later gate partials
    __shared__ ush h1P[3 * 8192];   // h1 planes (KC=8, MT=2); later fp32 h2
    __shared__ int lcount[NE], lbase[NE], lpos[32], lexp[32];

    const int tid  = threadIdx.x;
    const int row0 = blockIdx.x * 32;
    if (tid < NE) lcount[tid] = 0;

    {   // posenc: thread (row, g) writes 4 k's
        const int row = tid & 31, g = tid >> 5;
        const int i = row0 + row;
        const float xv[3] = {xyz[3 * i], xyz[3 * i + 1], xyz[3 * i + 2]};
        const int mt = row >> 4, m = row & 15;
        #pragma unroll
        for (int kk = 0; kk < 4; ++kk) {
            const int k = g * 4 + kk;
            float v = 0.f;
            if (k < 3) v = xv[k];
            else if (k < 63) {
                const int l = (k - 3) / 6, c = (k - 3) % 6;
                const float f = (float)(1 << l);
                v = (c < 3) ? sinf(f * xv[c]) : cosf(f * xv[c - 3]);
            }
            const int kc = k >> 5, qq = (k >> 3) & 3, j = k & 7;
            const int off = ((kc * 2 + mt) * 4 + qq) * 128 + m * 8 + j;
            ush hh, mm, ll; split3t(v, hh, mm, ll);
            exP[off] = hh; exP[2048 + off] = mm; exP[4096 + off] = ll;
        }
    }
    __syncthreads();

    const int lane = tid & 63, wv = tid >> 6;
    const int q = lane >> 4, n15 = lane & 15;

    // --- l1 = relu(ex @ W1 + b1) -> h1 planes ---
    f4 acc[2][2];
    #pragma unroll
    for (int a = 0; a < 2; ++a)
        #pragma unroll
        for (int b_ = 0; b_ < 2; ++b_) acc[a][b_] = (f4){0.f, 0.f, 0.f, 0.f};
    gemm3<2, 2, 2>(exP, W1p, lane, wv * 2, acc);
    #pragma unroll
    for (int nl = 0; nl < 2; ++nl) {
        const int col = wv * 32 + nl * 16 + n15;
        const float bias = b1[col];
        const int kc = col >> 5, qc = (col >> 3) & 3, jc = col & 7;
        #pragma unroll
        for (int mt = 0; mt < 2; ++mt)
            #pragma unroll
            for (int r = 0; r < 4; ++r) {
                const float v = fmaxf(acc[mt][nl][r] + bias, 0.f);
                const int off = ((kc * 2 + mt) * 4 + qc) * 128 + (q * 4 + r) * 8 + jc;
                ush hh, mm, ll; split3t(v, hh, mm, ll);
                h1P[off] = hh; h1P[8192 + off] = mm; h1P[16384 + off] = ll;
            }
    }
    __syncthreads();

    // --- l2 = h1 @ W2 + b2 ---
    #pragma unroll
    for (int a = 0; a < 2; ++a)
        #pragma unroll
        for (int b_ = 0; b_ < 2; ++b_) acc[a][b_] = (f4){0.f, 0.f, 0.f, 0.f};
    gemm3<8, 2, 2>(h1P, W2p, lane, wv * 2, acc);
    __syncthreads();                 // all h1 reads done before overlay

    float* h2f  = (float*)h1P;       // [32][259] (stride 259: conflict-free scalar)
    float* part = (float*)exP;       // [8][32][8] gate partials (exP dead)
    #pragma unroll
    for (int nl = 0; nl < 2; ++nl) {
        const int col = wv * 32 + nl * 16 + n15;
        const float bias = b2[col];
        #pragma unroll
        for (int mt = 0; mt < 2; ++mt)
            #pragma unroll
            for (int r = 0; r < 4; ++r) {
                const int row = mt * 16 + q * 4 + r;
                const float v = acc[mt][nl][r] + bias;
                h2p[(size_t)(row0 + row) * HD + col] = pack2t(v);
                h2f[row * 259 + col] = v;
            }
    }
    __syncthreads();

    // --- gate partials: 8 segs x 32 rows (256 threads), 32 k each ---
    if (tid < 256) {
        const int row = tid & 31, seg = tid >> 5, k0 = seg * 32;
        float lg[NE];
        #pragma unroll
        for (int e = 0; e < NE; ++e) lg[e] = 0.f;
        for (int k = k0; k < k0 + 32; ++k) {
            const float hv = h2f[row * 259 + k];
            const float4 w0 = *(const float4*)(Wg + k * 8);
            const float4 w1 = *(const float4*)(Wg + k * 8 + 4);
            lg[0] = fmaf(hv, w0.x, lg[0]); lg[1] = fmaf(hv, w0.y, lg[1]);
            lg[2] = fmaf(hv, w0.z, lg[2]); lg[3] = fmaf(hv, w0.w, lg[3]);
            lg[4] = fmaf(hv, w1.x, lg[4]); lg[5] = fmaf(hv, w1.y, lg[5]);
            lg[6] = fmaf(hv, w1.z, lg[6]); lg[7] = fmaf(hv, w1.w, lg[7]);
        }
        #pragma unroll
        for (int e = 0; e < NE; ++e) part[(seg * 32 + row) * 8 + e] = lg[e];
    }
    __syncthreads();

    if (tid < 32) {
        float lg[NE];
        #pragma unroll
        for (int e = 0; e < NE; ++e) {
            float s = bg[e];
            #pragma unroll
            for (int sg = 0; sg < 8; ++sg) s += part[(sg * 32 + tid) * 8 + e];
            lg[e] = s;
        }
        int best = 0; float mx = lg[0];
        #pragma unroll
        for (int e = 1; e < NE; ++e) if (lg[e] > mx) { mx = lg[e]; best = e; }
        float s = 0.f;
        #pragma unroll
        for (int e = 0; e < NE; ++e) s += expf(lg[e] - mx);
        gateout[row0 + tid] = 1.f / s;
        lexp[tid] = best;
        lpos[tid] = atomicAdd(&lcount[best], 1);
    }
    __syncthreads();
    if (tid < NE) lbase[tid] = atomicAdd(&counts[tid], lcount[tid]);
    __syncthreads();
    if (tid < 32) {
        const int e = lexp[tid];
        bucket[e * NS + lbase[e] + lpos[tid]] = row0 + tid;
    }
}

// ---------------------------------------------------------------------------
// Kernel 2: expert MLP + heads. 64 rows / block, 512 threads (8 waves, NTW=2).
// A in two bf16 planes, A-frag layout. LDS 78KB -> 2 blocks/CU (16 waves).
// Skip value re-read from L2-hot h2p at l1 epilogue (no register stash ->
// fits the 128-reg cap of launch_bounds(512,4) without scratch spills).
// ---------------------------------------------------------------------------
__global__ __launch_bounds__(512, 4) void expert_kernel(
    const unsigned* __restrict__ h2p, const float* __restrict__ gatebuf,
    const int* __restrict__ counts, const int* __restrict__ bucket,
    const ush* __restrict__ EWp, const float* __restrict__ be,
    const float* __restrict__ dirs,
    const ush* __restrict__ Ws1p, const float* __restrict__ bs1,
    const float* __restrict__ Ws2, const float* __restrict__ bs2,
    const ush* __restrict__ Wc1p, const float* __restrict__ bc1,
    const float* __restrict__ Wc2, const float* __restrict__ bc2,
    float* __restrict__ outp)
{
    __shared__ ush   Ah[9 * 2048];      // hi plane (KC=9 incl. dirs ext); later fp32 s
    __shared__ ush   Al[9 * 2048];      // lo plane;                       later fp32 c
    __shared__ float dotp[4 * 64 * 4];
    __shared__ int   idx[64];
    __shared__ float gatev[64];

    const int tid = threadIdx.x;
    const int e   = blockIdx.x >> 10;
    const int t   = blockIdx.x & 1023;
    const int cnt = counts[e];
    if (t * 64 >= cnt) return;
    const int nact = min(64, cnt - t * 64);

    if (tid < 64) {
        const int src = bucket[e * NS + t * 64 + min(tid, nact - 1)];
        idx[tid]   = src;
        gatev[tid] = gatebuf[src];
    }
    __syncthreads();

    const int lane = tid & 63, wv = tid >> 6;
    const int q = lane >> 4, n15 = lane & 15;

    {   // gather: wave wv -> kc=wv, lane = row; unpack packed h2 into planes
        const int row = lane, mt = row >> 4, m = row & 15;
        const unsigned* src = h2p + (size_t)idx[row] * HD + wv * 32;
        #pragma unroll
        for (int sub = 0; sub < 4; ++sub) {
            bh8 hv, lv;
            unpack8(src + sub * 8, hv, lv);
            const int off = ((wv * 4 + mt) * 4 + sub) * 128 + m * 8;
            *(bh8*)(Ah + off) = hv;
            *(bh8*)(Al + off) = lv;
        }
    }
    if (tid < 64) {   // dirs posenc ext -> kc=8 region
        const int row = tid, i = idx[row];
        const int mt = row >> 4, m = row & 15;
        const float d0 = dirs[3 * i], d1 = dirs[3 * i + 1], d2 = dirs[3 * i + 2];
        float vals[32];
        vals[0] = d0; vals[1] = d1; vals[2] = d2;
        float f = 1.f;
        #pragma unroll
        for (int l = 0; l < 4; ++l) {
            vals[3 + 6 * l + 0] = sinf(f * d0);
            vals[3 + 6 * l + 1] = sinf(f * d1);
            vals[3 + 6 * l + 2] = sinf(f * d2);
            vals[3 + 6 * l + 3] = cosf(f * d0);
            vals[3 + 6 * l + 4] = cosf(f * d1);
            vals[3 + 6 * l + 5] = cosf(f * d2);
            f *= 2.f;
        }
        #pragma unroll
        for (int c = 27; c < 32; ++c) vals[c] = 0.f;
        #pragma unroll
        for (int k2 = 0; k2 < 32; ++k2) {
            const int off = ((8 * 4 + mt) * 4 + (k2 >> 3)) * 128 + m * 8 + (k2 & 7);
            ush hh, ll; split2t(vals[k2], hh, ll);
            Ah[off] = hh; Al[off] = ll;
        }
    }
    __syncthreads();

    const float* bb = be + e * 4 * HD;
    const ush* W0 = EWp + (size_t)(e * 4) * 131072;

    // ---- l0: A <- relu(A @ W0 + b0) ----
    {
        f4 acc[4][2];
        #pragma unroll
        for (int mt = 0; mt < 4; ++mt)
            #pragma unroll
            for (int nl = 0; nl < 2; ++nl) acc[mt][nl] = (f4){0.f, 0.f, 0.f, 0.f};
        gemm2p<8, 2, 16, 4>(Ah, Al, W0, W0 + 65536, lane, wv * 2, acc);
        __syncthreads();
        #pragma unroll
        for (int nl = 0; nl < 2; ++nl) {
            const int col = wv * 32 + nl * 16 + n15;
            const float bias = bb[col];
            const int kc = col >> 5, qc = (col >> 3) & 3, jc = col & 7;
            #pragma unroll
            for (int mt = 0; mt < 4; ++mt)
                #pragma unroll
                for (int r = 0; r < 4; ++r) {
                    const int off = ((kc * 4 + mt) * 4 + qc) * 128 + (q * 4 + r) * 8 + jc;
                    const float v = fmaxf(acc[mt][nl][r] + bias, 0.f);
                    ush hh, ll; split2t(v, hh, ll);
                    Ah[off] = hh; Al[off] = ll;
                }
        }
        __syncthreads();
    }
    // ---- l1: A <- relu(A @ W1 + b1 + skip)   (skip re-read from L2-hot h2p) ----
    {
        f4 acc[4][2];
        #pragma unroll
        for (int mt = 0; mt < 4; ++mt)
            #pragma unroll
            for (int nl = 0; nl < 2; ++nl) acc[mt][nl] = (f4){0.f, 0.f, 0.f, 0.f};
        gemm2p<8, 2, 16, 4>(Ah, Al, W0 + 131072, W0 + 131072 + 65536, lane, wv * 2, acc);
        __syncthreads();
        #pragma unroll
        for (int nl = 0; nl < 2; ++nl) {
            const int col = wv * 32 + nl * 16 + n15;
            const float bias = bb[256 + col];
            const int kc = col >> 5, qc = (col >> 3) & 3, jc = col & 7;
            #pragma unroll
            for (int mt = 0; mt < 4; ++mt)
                #pragma unroll
                for (int r = 0; r < 4; ++r) {
                    const int row = mt * 16 + q * 4 + r;
                    const int off = ((kc * 4 + mt) * 4 + qc) * 128 + (q * 4 + r) * 8 + jc;
                    const float sk = unpackf(h2p[(size_t)idx[row] * HD + col]);
                    const float v = fmaxf(acc[mt][nl][r] + bias + sk, 0.f);
                    ush hh, ll; split2t(v, hh, ll);
                    Ah[off] = hh; Al[off] = ll;
                }
        }
        __syncthreads();
    }
    // ---- l2: A <- relu(A @ W2 + b2) ----
    {
        f4 acc[4][2];
        #pragma unroll
        for (int mt = 0; mt < 4; ++mt)
            #pragma unroll
            for (int nl = 0; nl < 2; ++nl) acc[mt][nl] = (f4){0.f, 0.f, 0.f, 0.f};
        gemm2p<8, 2, 16, 4>(Ah, Al, W0 + 2 * 131072, W0 + 2 * 131072 + 65536, lane, wv * 2, acc);
        __syncthreads();
        #pragma unroll
        for (int nl = 0; nl < 2; ++nl) {
            const int col = wv * 32 + nl * 16 + n15;
            const float bias = bb[512 + col];
            const int kc = col >> 5, qc = (col >> 3) & 3, jc = col & 7;
            #pragma unroll
            for (int mt = 0; mt < 4; ++mt)
                #pragma unroll
                for (int r = 0; r < 4; ++r) {
                    const int off = ((kc * 4 + mt) * 4 + qc) * 128 + (q * 4 + r) * 8 + jc;
                    const float v = fmaxf(acc[mt][nl][r] + bias, 0.f);
                    ush hh, ll; split2t(v, hh, ll);
                    Ah[off] = hh; Al[off] = ll;
                }
        }
        __syncthreads();
    }
    // ---- l3: A <- gate * (A @ W3 + b3)  (no relu) ----
    {
        f4 acc[4][2];
        #pragma unroll
        for (int mt = 0; mt < 4; ++mt)
            #pragma unroll
            for (int nl = 0; nl < 2; ++nl) acc[mt][nl] = (f4){0.f, 0.f, 0.f, 0.f};
        gemm2p<8, 2, 16, 4>(Ah, Al, W0 + 3 * 131072, W0 + 3 * 131072 + 65536, lane, wv * 2, acc);
        __syncthreads();
        #pragma unroll
        for (int nl = 0; nl < 2; ++nl) {
            const int col = wv * 32 + nl * 16 + n15;
            const float bias = bb[768 + col];
            const int kc = col >> 5, qc = (col >> 3) & 3, jc = col & 7;
            #pragma unroll
            for (int mt = 0; mt < 4; ++mt)
                #pragma unroll
                for (int r = 0; r < 4; ++r) {
                    const int row = mt * 16 + q * 4 + r;
                    const int off = ((kc * 4 + mt) * 4 + qc) * 128 + (q * 4 + r) * 8 + jc;
                    const float v = gatev[row] * (acc[mt][nl][r] + bias);
                    ush hh, ll; split2t(v, hh, ll);
                    Ah[off] = hh; Al[off] = ll;
                }
        }
        __syncthreads();
    }

    // ---- heads: s = relu(out@Ws1+bs1), c = relu([out,ed]@Wc1+bc1) ----
    {
        f4 sacc[4][1], cacc[4][1];
        #pragma unroll
        for (int mt = 0; mt < 4; ++mt) {
            sacc[mt][0] = (f4){0.f, 0.f, 0.f, 0.f};
            cacc[mt][0] = (f4){0.f, 0.f, 0.f, 0.f};
        }
        gemm2p<8, 1, 8, 4>(Ah, Al, Ws1p, Ws1p + 32768, lane, wv, sacc);
        gemm2p<9, 1, 8, 4>(Ah, Al, Wc1p, Wc1p + 36864, lane, wv, cacc);
        __syncthreads();
        float* sp = (float*)Ah;          // [64][133]
        float* cp = (float*)Al;
        const int col = wv * 16 + n15;
        const float b_s = bs1[col], b_c = bc1[col];
        #pragma unroll
        for (int mt = 0; mt < 4; ++mt)
            #pragma unroll
            for (int r = 0; r < 4; ++r) {
                const int row = mt * 16 + q * 4 + r;
                sp[row * 133 + col] = fmaxf(sacc[mt][0][r] + b_s, 0.f);
                cp[row * 133 + col] = fmaxf(cacc[mt][0][r] + b_c, 0.f);
            }
        __syncthreads();
    }
    // ---- final dots: 4 segs x 64 rows, 32 k each ----
    if (tid < 256) {
        const float* sp = (const float*)Ah;
        const float* cp = (const float*)Al;
        const int row = tid & 63, seg = tid >> 6, k0 = seg * 32;
        float ps = 0.f, p0 = 0.f, p1 = 0.f, p2 = 0.f;
        for (int k = k0; k < k0 + 32; ++k) {
            ps = fmaf(sp[row * 133 + k], Ws2[k], ps);
            const float cv = cp[row * 133 + k];
            p0 = fmaf(cv, Wc2[3 * k + 0], p0);
            p1 = fmaf(cv, Wc2[3 * k + 1], p1);
            p2 = fmaf(cv, Wc2[3 * k + 2], p2);
        }
        *(float4*)&dotp[(seg * 64 + row) * 4] = make_float4(ps, p0, p1, p2);
    }
    __syncthreads();
    if (tid < nact) {
        float sg = bs2[0], r0 = bc2[0], r1 = bc2[1], r2 = bc2[2];
        #pragma unroll
        for (int s2 = 0; s2 < 4; ++s2) {
            const float4 pv = *(const float4*)&dotp[(s2 * 64 + tid) * 4];
            sg += pv.x; r0 += pv.y; r1 += pv.z; r2 += pv.w;
        }
        float4 o;
        o.x = 1.f / (1.f + expf(-r0));
        o.y = 1.f / (1.f + expf(-r1));
        o.z = 1.f / (1.f + expf(-r2));
        o.w = fmaxf(sg, 0.f) + log1pf(expf(-fabsf(sg)));
        *(float4*)&outp[(size_t)idx[tid] * 4] = o;
    }
}

// ---------------------------------------------------------------------------
extern "C" void kernel_launch(void* const* d_in, const int* in_sizes, int n_in,
                              void* d_out, int out_size, void* d_ws, size_t ws_size,
                              hipStream_t stream)
{
    const float* xyz  = (const float*)d_in[0];
    const float* dirs = (const float*)d_in[1];
    const float* W1   = (const float*)d_in[2];
    const float* b1   = (const float*)d_in[3];
    const float* W2   = (const float*)d_in[4];
    const float* b2   = (const float*)d_in[5];
    const float* Wg   = (const float*)d_in[6];
    const float* bg   = (const float*)d_in[7];
    const float* We   = (const float*)d_in[8];
    const float* be   = (const float*)d_in[9];
    const float* Ws1  = (const float*)d_in[10];
    const float* bs1  = (const float*)d_in[11];
    const float* Ws2  = (const float*)d_in[12];
    const float* bs2  = (const float*)d_in[13];
    const float* Wc1  = (const float*)d_in[14];
    const float* bc1  = (const float*)d_in[15];
    const float* Wc2  = (const float*)d_in[16];
    const float* bc2  = (const float*)d_in[17];
    float* out = (float*)d_out;

    char* ws = (char*)d_ws;
    unsigned* h2p     = (unsigned*)ws;                        // 64 MB packed h2
    float*    gatebuf = (float*)(ws + 67108864);              // 256 KB
    int*      counts  = (int*)(ws + 67371008);                // 1 KB (padded)
    int*      bucket  = (int*)(ws + 67372032);                // 2 MB
    ush*      EWp     = (ush*)(ws + 69469184);                // 8 MB expert frags
    ush*      Ws1p    = (ush*)(ws + 77857792);                // 128 KB
    ush*      Wc1p    = (ush*)(ws + 77988864);                // 144 KB
    ush*      W1p     = (ush*)(ws + 78136320);                // 96 KB  (3 planes)
    ush*      W2p     = (ush*)(ws + 78234624);                // 384 KB (3 planes)

    hipMemsetAsync(counts, 0, NE * sizeof(int), stream);
    prep_expert<<<1024, 256, 0, stream>>>(We, EWp);
    prep_head<<<16, 256, 0, stream>>>(Ws1, Ws1p, 8, 256);
    prep_head<<<18, 256, 0, stream>>>(Wc1, Wc1p, 9, 283);
    prep_trunk3<<<8, 256, 0, stream>>>(W1, W1p, 2, 63);
    prep_trunk3<<<32, 256, 0, stream>>>(W2, W2p, 8, 256);
    trunk_kernel<<<NS / 32, 512, 0, stream>>>(xyz, W1p, b1, W2p, b2, Wg, bg,
                                              h2p, gatebuf, counts, bucket);
    expert_kernel<<<NE * 1024, 512, 0, stream>>>(h2p, gatebuf, counts, bucket,
                                                 EWp, be, dirs, Ws1p, bs1, Ws2, bs2,
                                                 Wc1p, bc1, Wc2, bc2, out);
}